// Round 1
// baseline (808.887 us; speedup 1.0000x reference)
//
#include <hip/hip_runtime.h>
#include <cmath>

#define PI_F 3.14159265358979323846f
#define NTOK 128
#define NPIX 16384
#define NHEADS 16

__device__ __forceinline__ void block_reduce2(float& a, float& b){
  __shared__ float sa[4], sb[4];
  __syncthreads();  // protect sa/sb from a previous call's readers
  for (int o=32;o>0;o>>=1){ a += __shfl_down(a,o); b += __shfl_down(b,o); }
  int w = threadIdx.x>>6, l = threadIdx.x&63;
  if (l==0){ sa[w]=a; sb[w]=b; }
  __syncthreads();
  a = sa[0]+sa[1]+sa[2]+sa[3];
  b = sb[0]+sb[1]+sb[2]+sb[3];
}

// ---- Stage 1: instance-norm of x -> tn -------------------------------------
__global__ __launch_bounds__(256) void k_norm_x(const float* __restrict__ x, const float* __restrict__ g,
                         const float* __restrict__ b, float* __restrict__ tn){
  int s = blockIdx.x;
  const float* xs = x + (size_t)s*NPIX;
  float* ts = tn + (size_t)s*NPIX;
  float sum=0.f, sq=0.f;
  for (int i=threadIdx.x;i<NPIX;i+=256){ float v=xs[i]; sum+=v; sq+=v*v; }
  block_reduce2(sum,sq);
  float mu = sum*(1.f/NPIX);
  float var = sq*(1.f/NPIX) - mu*mu;
  float inv = rsqrtf(var + 1e-5f) * g[0];
  float bb = b[0];
  for (int i=threadIdx.x;i<NPIX;i+=256) ts[i] = (xs[i]-mu)*inv + bb;
}

// ---- Column DFT (along w): A[row,c] = sum_w in[row,w] e^{-2pi i c w/128} ---
template<int CMAX>
__global__ __launch_bounds__(256) void k_colfft(const float* __restrict__ in, float* __restrict__ A){
  __shared__ float rows[32*128];
  __shared__ float tw[128][2];
  int base = blockIdx.x*32;  // global row index (token*128 + h)
  for (int i=threadIdx.x;i<32*128;i+=256) rows[i] = in[(size_t)base*128 + i];
  for (int p=threadIdx.x;p<128;p+=256){
    float sn,cs; sincosf(-(2.f*PI_F/128.f)*(float)p, &sn,&cs); tw[p][0]=cs; tw[p][1]=sn;
  }
  __syncthreads();
  for (int e=threadIdx.x; e<32*CMAX; e+=256){
    int r = e/CMAX, c = e%CMAX;
    const float* rp = rows + r*128;
    float re=0.f, im=0.f;
    for (int w=0;w<128;w++){
      int p = (c*w)&127;
      float v = rp[w];
      re += v*tw[p][0]; im += v*tw[p][1];
    }
    float* o = A + ((size_t)(base + r)*CMAX + c)*2;
    o[0]=re; o[1]=im;
  }
}

// ---- Row DFT for 64x33 spectrum (rows 0..31 and 96..127), with 1/16384 -----
__global__ __launch_bounds__(256) void k_rowfft64(const float* __restrict__ A, float* __restrict__ X64){
  int s = blockIdx.x;
  __shared__ float a[128*33*2];
  __shared__ float tw[128][2];
  for (int i=threadIdx.x;i<128*33*2;i+=256) a[i] = A[(size_t)s*(128*33*2) + i];
  for (int p=threadIdx.x;p<128;p+=256){ float sn,cs; sincosf(-(2.f*PI_F/128.f)*(float)p,&sn,&cs); tw[p][0]=cs; tw[p][1]=sn; }
  __syncthreads();
  const float sc = 1.f/16384.f;
  for (int e=threadIdx.x;e<64*33;e+=256){
    int i2=e/33, c=e%33;
    int r = (i2<32)? i2 : i2+64;
    float re=0.f, im=0.f;
    for (int h=0;h<128;h++){
      int p=(r*h)&127;
      float cs=tw[p][0], sn=tw[p][1];
      float ar=a[(h*33+c)*2], ai=a[(h*33+c)*2+1];
      re += ar*cs - ai*sn;
      im += ar*sn + ai*cs;
    }
    float* o = X64 + ((size_t)s*(64*33) + e)*2;
    o[0]=re*sc; o[1]=im*sc;
  }
}

// ---- Fourier resample of tn to 64x64 (full 64x33 spectrum inverse) ---------
__global__ __launch_bounds__(256) void k_res64(const float* __restrict__ X64, float* __restrict__ res){
  int s = blockIdx.x;
  __shared__ float Xs[64*33*2];
  __shared__ float T[64*33*2];
  __shared__ float tw[64][2];
  for (int i=threadIdx.x;i<64*33*2;i+=256) Xs[i] = X64[(size_t)s*(64*33*2)+i];
  for (int p=threadIdx.x;p<64;p+=256){ float sn,cs; sincosf((2.f*PI_F/64.f)*(float)p,&sn,&cs); tw[p][0]=cs; tw[p][1]=sn; }
  __syncthreads();
  for (int e=threadIdx.x;e<64*33;e+=256){
    int h=e/33, c=e%33;
    float re=0.f, im=0.f;
    for (int zr=0;zr<64;zr++){
      int p=(zr*h)&63;
      float cs=tw[p][0], sn=tw[p][1];
      float ar=Xs[(zr*33+c)*2], ai=Xs[(zr*33+c)*2+1];
      re += ar*cs - ai*sn;
      im += ar*sn + ai*cs;
    }
    T[e*2]=re; T[e*2+1]=im;
  }
  __syncthreads();
  for (int pos=threadIdx.x; pos<4096; pos+=256){
    int h=pos>>6, w=pos&63;
    const float* Th = T + (h*33)*2;
    float v = Th[0];  // Re only (C2R drops Im at c=0)
    for (int c=1;c<32;c++){
      int p=(c*w)&63;
      v += 2.f*(Th[c*2]*tw[p][0] - Th[c*2+1]*tw[p][1]);
    }
    { int p=(32*w)&63; v += Th[32*2]*tw[p][0]; }  // Nyquist col, not doubled
    res[(size_t)s*4096+pos] = v;
  }
}

// ---- K and Q fields (64x64 per token-head): spectral conv + skip -----------
__global__ __launch_bounds__(256) void k_kq(const float* __restrict__ X64, const float* __restrict__ res,
                     const float* __restrict__ wk, const float* __restrict__ skw, const float* __restrict__ skb,
                     const float* __restrict__ wq, const float* __restrict__ sqw, const float* __restrict__ sqb,
                     float* __restrict__ kout, float* __restrict__ qout){
  int s = blockIdx.x, o = blockIdx.y, z = blockIdx.z;
  const float* w  = z? wq : wk;
  const float* sw = z? sqw : skw;
  const float* sb = z? sqb : skb;
  float* out = z? qout : kout;
  __shared__ float S[16*9*2];
  __shared__ float T[64*9*2];
  __shared__ float tw[64][2];
  if (threadIdx.x < 64){ int p=threadIdx.x; float sn,cs; sincosf((2.f*PI_F/64.f)*(float)p,&sn,&cs); tw[p][0]=cs; tw[p][1]=sn; }
  for (int e=threadIdx.x;e<16*9;e+=256){
    int j=e/9, c=e%9;
    int i2 = (j<8)? j : (j+48);           // X64 storage row (Xft rows 0..7, 120..127)
    const float* xp = X64 + (((size_t)s*(64*33)) + i2*33 + c)*2;
    const float* wp = w + ((size_t)(o*16+j)*9 + c)*2;
    float xr=xp[0], xi=xp[1], wr=wp[0], wi=wp[1];
    S[e*2]   = xr*wr - xi*wi;
    S[e*2+1] = xr*wi + xi*wr;
  }
  __syncthreads();
  for (int e=threadIdx.x;e<64*9;e+=256){
    int h=e/9, c=e%9;
    float re=0.f, im=0.f;
    for (int j=0;j<16;j++){
      int zr = (j<8)? j : (j+48);         // rows 0..7 and 56..63 of the 64-grid
      int p=(zr*h)&63;
      float cs=tw[p][0], sn=tw[p][1];
      float ar=S[(j*9+c)*2], ai=S[(j*9+c)*2+1];
      re += ar*cs - ai*sn;
      im += ar*sn + ai*cs;
    }
    T[e*2]=re; T[e*2+1]=im;
  }
  __syncthreads();
  float swo = sw[o], sbo = sb[o];
  for (int pos=threadIdx.x;pos<4096;pos+=256){
    int h=pos>>6, wv=pos&63;
    const float* Th = T + (h*9)*2;
    float v = Th[0];
    for (int c=1;c<9;c++){
      int p=(c*wv)&63;
      v += 2.f*(Th[c*2]*tw[p][0] - Th[c*2+1]*tw[p][1]);
    }
    v += res[(size_t)s*4096+pos]*swo + sbo;
    out[((size_t)(s*16+o))*4096 + pos] = v;
  }
}

// ---- attention scores: P[b,h,t,s] = q.k / 64 -------------------------------
__global__ __launch_bounds__(256) void k_scores(const float* __restrict__ q, const float* __restrict__ k, float* __restrict__ P){
  int b=blockIdx.x, h=blockIdx.y;
  __shared__ float Qs[32][129], Ks[32][129];
  int tr = threadIdx.x>>4, tc = threadIdx.x&15;
  float acc00=0,acc01=0,acc10=0,acc11=0;
  for (int d0=0; d0<4096; d0+=128){
    for (int i=threadIdx.x;i<4096;i+=256){
      int t=i>>7, d=i&127;
      size_t qi = ((size_t)((b*32+t)*16+h))*4096 + d0 + d;
      Qs[t][d] = q[qi];
      Ks[t][d] = k[qi];
    }
    __syncthreads();
    for (int d=0; d<128; d++){
      float q0=Qs[2*tr][d], q1=Qs[2*tr+1][d];
      float k0=Ks[2*tc][d], k1=Ks[2*tc+1][d];
      acc00+=q0*k0; acc01+=q0*k1; acc10+=q1*k0; acc11+=q1*k1;
    }
    __syncthreads();
  }
  const float sc = 1.f/64.f;
  size_t base = ((size_t)(b*16+h))*1024;
  P[base + (2*tr)*32   + 2*tc]   = acc00*sc;
  P[base + (2*tr)*32   + 2*tc+1] = acc01*sc;
  P[base + (2*tr+1)*32 + 2*tc]   = acc10*sc;
  P[base + (2*tr+1)*32 + 2*tc+1] = acc11*sc;
}

__global__ __launch_bounds__(64) void k_softmax(float* __restrict__ P){
  int bh = blockIdx.x, t = blockIdx.y;
  size_t base = ((size_t)bh*32 + t)*32;
  int l = threadIdx.x;
  float v = (l<32)? P[base+l] : -INFINITY;
  float m = v;
  for (int o=32;o>0;o>>=1) m = fmaxf(m, __shfl_xor(m,o));
  float e = (l<32)? expf(v-m) : 0.f;
  float ssum = e;
  for (int o=32;o>0;o>>=1) ssum += __shfl_xor(ssum,o);
  if (l<32) P[base+l] = e/ssum;
}

// ---- R[b,t,s] = sum_h pw[h]*vw[h]*P[b,h,t,s] -------------------------------
__global__ __launch_bounds__(64) void k_R(const float* __restrict__ P, const float* __restrict__ pw,
                    const float* __restrict__ vw, float* __restrict__ R){
  int b=blockIdx.x, t=blockIdx.y;
  int s2=threadIdx.x;
  if (s2<32){
    float acc=0.f;
    for (int h=0;h<16;h++)
      acc += pw[h]*vw[h]*P[(((size_t)(b*16+h)*32)+t)*32 + s2];
    R[((size_t)(b*32+t))*32 + s2] = acc;
  }
}

// ---- XP[b,h,t] = sum_s P[b,h,t,s] * X32(token b,s)  (32x17 modes) ----------
__global__ __launch_bounds__(256) void k_XP(const float* __restrict__ P, const float* __restrict__ X64, float* __restrict__ XP){
  int b=blockIdx.x, h=blockIdx.y, t=blockIdx.z;
  __shared__ float Pr[32];
  if (threadIdx.x<32) Pr[threadIdx.x] = P[(((size_t)(b*16+h)*32)+t)*32 + threadIdx.x];
  __syncthreads();
  size_t obase = ((size_t)((b*16+h)*32+t))*544;
  for (int e=threadIdx.x;e<544;e+=256){
    int j=e/17, c=e%17;
    int i2 = (j<16)? j : (j+32);   // X64 storage rows: 0..15 and 48..63 (Xft 112..127)
    float re=0.f, im=0.f;
    for (int s2=0;s2<32;s2++){
      const float* xp = X64 + (((size_t)(b*32+s2))*(64*33) + i2*33 + c)*2;
      float p = Pr[s2];
      re += p*xp[0]; im += p*xp[1];
    }
    XP[(obase+e)*2]=re; XP[(obase+e)*2+1]=im;
  }
}

// ---- final per-token proj spectrum (32x17) with hermitian-c0 projection ----
__global__ __launch_bounds__(256) void k_Sfin(const float* __restrict__ XP,
                       const float* __restrict__ value_w, const float* __restrict__ vsw, const float* __restrict__ vsb,
                       const float* __restrict__ proj_w, const float* __restrict__ psw,
                       float* __restrict__ Sfin){
  int bt=blockIdx.x; int b=bt>>5, t=bt&31;
  __shared__ float XPs[544*2];
  float ar[3]={0,0,0}, ai[3]={0,0,0};
  for (int h=0;h<16;h++){
    __syncthreads();
    const float* src = XP + (((size_t)((b*16+h)*32+t))*544)*2;
    for (int i=threadIdx.x;i<1088;i+=256) XPs[i]=src[i];
    __syncthreads();
    float vw = vsw[h], vb = vsb[h], pw = psw[h];
    for (int u=0;u<3;u++){
      int e = threadIdx.x + u*256;
      if (e>=544) break;
      int j=e/17, c=e%17;
      float xr=XPs[e*2], xi=XPs[e*2+1];
      float wvr=0.f, wvi=0.f;
      if (c<=8 && (j<8 || j>=24)){                 // v-mode support
        int jw = (j<8)? j : (j-16);                // value_w row
        const float* wv = value_w + ((size_t)(h*16+jw)*9 + c)*2;
        wvr=wv[0]; wvi=wv[1];
      }
      float Mr = xr*wvr - xi*wvi;                  // M = XP * Wv
      float Mi = xr*wvi + xi*wvr;
      float Mhr=Mr, Mhi=Mi;
      if (c==0){                                   // hermitian projection at col 0
        float Pr2=0.f, Pi2=0.f;
        int jp2 = (j==0)? 0 : ((j==16)? -1 : 32-j);
        if (jp2>=0 && (jp2<8 || jp2>=24)){
          int jw2 = (jp2<8)? jp2 : (jp2-16);
          const float* wv2 = value_w + ((size_t)(h*16+jw2)*9)*2;
          float pxr=XPs[(jp2*17)*2], pxi=XPs[(jp2*17)*2+1];
          Pr2 = pxr*wv2[0] - pxi*wv2[1];
          Pi2 = pxr*wv2[1] + pxi*wv2[0];
        }
        Mhr = 0.5f*(Mr + Pr2);
        Mhi = 0.5f*(Mi - Pi2);
      }
      float Yr = vw*xr + Mhr + ((e==0)? vb : 0.f); // rfft2(attn[h]) on proj support
      float Yi = vw*xi + Mhi;
      const float* pc = proj_w + ((size_t)(h*32+j)*17 + c)*2;
      float pr=pc[0], pi=pc[1];
      ar[u] += pr*Yr - pi*Yi + pw*Mr;              // + pw*Mv (skip path, folded)
      ai[u] += pr*Yi + pi*Yr + pw*Mi;
    }
  }
  for (int u=0;u<3;u++){
    int e = threadIdx.x + u*256;
    if (e<544){ Sfin[((size_t)bt*544+e)*2]=ar[u]; Sfin[((size_t)bt*544+e)*2+1]=ai[u]; }
  }
}

// ---- skipmix[b,t,:] = sum_s R[b,t,s]*tn[b,s,:] -----------------------------
__global__ __launch_bounds__(256) void k_skipmix(const float* __restrict__ tn, const float* __restrict__ R, float* __restrict__ out){
  int b=blockIdx.x, ch=blockIdx.y;
  int base = ch*512;
  __shared__ float Rs[32][32];
  for (int i=threadIdx.x;i<1024;i+=256) Rs[i>>5][i&31] = R[(size_t)b*1024 + i];
  __syncthreads();
  float a0[32], a1[32];
  #pragma unroll
  for (int t2=0;t2<32;t2++){ a0[t2]=0.f; a1[t2]=0.f; }
  for (int s2=0;s2<32;s2++){
    const float* tp = tn + ((size_t)(b*32+s2))*NPIX + base;
    float v0 = tp[threadIdx.x], v1 = tp[threadIdx.x+256];
    #pragma unroll
    for (int t2=0;t2<32;t2++){ float r=Rs[t2][s2]; a0[t2]+=r*v0; a1[t2]+=r*v1; }
  }
  #pragma unroll
  for (int t2=0;t2<32;t2++){
    float* op = out + ((size_t)(b*32+t2))*NPIX + base;
    op[threadIdx.x]=a0[t2]; op[threadIdx.x+256]=a1[t2];
  }
}

// ---- proj finalize: irfft128 + skip + residual + 2 instance norms ----------
__global__ __launch_bounds__(256) void k_proj_final(const float* __restrict__ Sfin, const float* __restrict__ skipmix,
                             const float* __restrict__ x,
                             const float* __restrict__ psw, const float* __restrict__ vsb, const float* __restrict__ psb,
                             const float* __restrict__ ag, const float* __restrict__ ab,
                             const float* __restrict__ n2g, const float* __restrict__ n2b,
                             float* __restrict__ attn2, float* __restrict__ m0){
  int bt=blockIdx.x;
  __shared__ float Ss[544*2];
  __shared__ float T[128*17*2];
  __shared__ float tw[128][2];
  for (int i=threadIdx.x;i<1088;i+=256) Ss[i] = Sfin[(size_t)bt*1088 + i];
  for (int p=threadIdx.x;p<128;p+=256){ float sn,cs; sincosf((2.f*PI_F/128.f)*(float)p,&sn,&cs); tw[p][0]=cs; tw[p][1]=sn; }
  __syncthreads();
  for (int e=threadIdx.x;e<128*17;e+=256){
    int h=e/17, c=e%17;
    float re=0.f, im=0.f;
    for (int j=0;j<32;j++){
      int r = (j<16)? j : (j+96);
      int p=(r*h)&127;
      float cs=tw[p][0], sn=tw[p][1];
      float arv=Ss[(j*17+c)*2], aiv=Ss[(j*17+c)*2+1];
      re += arv*cs - aiv*sn;
      im += arv*sn + aiv*cs;
    }
    T[e*2]=re; T[e*2+1]=im;
  }
  __syncthreads();
  float Cb = psb[0];
  for (int h=0;h<16;h++) Cb += psw[h]*vsb[h];
  float sum=0.f,sq=0.f;
  float* zb = attn2 + (size_t)bt*NPIX;
  const float* sm = skipmix + (size_t)bt*NPIX;
  const float* xs = x + (size_t)bt*NPIX;
  for (int pos=threadIdx.x;pos<NPIX;pos+=256){
    int h=pos>>7, w=pos&127;
    const float* Th = T + (h*17)*2;
    float v = Th[0];
    for (int c=1;c<17;c++){
      int p=(c*w)&127;
      v += 2.f*(Th[c*2]*tw[p][0] - Th[c*2+1]*tw[p][1]);
    }
    v += sm[pos] + Cb + xs[pos];
    zb[pos]=v; sum+=v; sq+=v*v;
  }
  block_reduce2(sum,sq);
  float mu = sum*(1.f/NPIX);
  float inv = rsqrtf(sq*(1.f/NPIX)-mu*mu + 1e-5f);
  float g1=ag[0], b1=ab[0];
  float sum2=0.f,sq2=0.f;
  for (int pos=threadIdx.x;pos<NPIX;pos+=256){
    float a = (zb[pos]-mu)*inv*g1 + b1;
    zb[pos]=a; sum2+=a; sq2+=a*a;
  }
  block_reduce2(sum2,sq2);
  float mu2 = sum2*(1.f/NPIX);
  float inv2 = rsqrtf(sq2*(1.f/NPIX)-mu2*mu2 + 1e-5f);
  float g2=n2g[0], b2=n2b[0];
  float* m0p = m0 + (size_t)bt*NPIX;
  for (int pos=threadIdx.x;pos<NPIX;pos+=256)
    m0p[pos] = (zb[pos]-mu2)*inv2*g2 + b2;
}

// ---- forward 32x17 modes (rows 0..15, 112..127) for mixer ------------------
__global__ __launch_bounds__(256) void k_rowfft32(const float* __restrict__ A, float* __restrict__ spec){
  int s=blockIdx.x;
  __shared__ float a[128*17*2];
  __shared__ float tw[128][2];
  for (int i=threadIdx.x;i<128*17*2;i+=256) a[i]=A[(size_t)s*(128*17*2)+i];
  for (int p=threadIdx.x;p<128;p+=256){ float sn,cs; sincosf(-(2.f*PI_F/128.f)*(float)p,&sn,&cs); tw[p][0]=cs; tw[p][1]=sn; }
  __syncthreads();
  const float sc=1.f/16384.f;
  for (int e=threadIdx.x;e<544;e+=256){
    int j=e/17, c=e%17;
    int r=(j<16)? j : (j+96);
    float re=0.f,im=0.f;
    for (int h=0;h<128;h++){
      int p=(r*h)&127;
      float cs=tw[p][0], sn=tw[p][1];
      float ar=a[(h*17+c)*2], ai=a[(h*17+c)*2+1];
      re += ar*cs - ai*sn;
      im += ar*sn + ai*cs;
    }
    spec[((size_t)s*544+e)*2]=re*sc; spec[((size_t)s*544+e)*2+1]=im*sc;
  }
}

// ---- one mixer FNO layer: irfft(spec*w) -> inst-norm -> +skip -> (gelu) ----
__global__ __launch_bounds__(256) void k_mixer(const float* __restrict__ spec, const float* __restrict__ wm,
                        const float* __restrict__ skipsrc, const float* __restrict__ sw, const float* __restrict__ sb,
                        const float* __restrict__ ng, const float* __restrict__ nb,
                        float* __restrict__ xfb, float* __restrict__ out, int do_gelu){
  int bt=blockIdx.x;
  __shared__ float Ss[544*2];
  __shared__ float T[128*17*2];
  __shared__ float tw[128][2];
  for (int e=threadIdx.x;e<544;e+=256){
    float xr=spec[((size_t)bt*544+e)*2], xi=spec[((size_t)bt*544+e)*2+1];
    float wr=wm[e*2], wi=wm[e*2+1];
    Ss[e*2]=xr*wr-xi*wi; Ss[e*2+1]=xr*wi+xi*wr;
  }
  for (int p=threadIdx.x;p<128;p+=256){ float sn,cs; sincosf((2.f*PI_F/128.f)*(float)p,&sn,&cs); tw[p][0]=cs; tw[p][1]=sn; }
  __syncthreads();
  for (int e=threadIdx.x;e<128*17;e+=256){
    int h=e/17, c=e%17;
    float re=0.f,im=0.f;
    for (int j=0;j<32;j++){
      int r=(j<16)? j:(j+96);
      int p=(r*h)&127;
      float cs=tw[p][0], sn=tw[p][1];
      float ar=Ss[(j*17+c)*2], ai=Ss[(j*17+c)*2+1];
      re += ar*cs-ai*sn; im += ar*sn+ai*cs;
    }
    T[e*2]=re; T[e*2+1]=im;
  }
  __syncthreads();
  float sum=0.f,sq=0.f;
  float* xp = xfb + (size_t)bt*NPIX;
  for (int pos=threadIdx.x;pos<NPIX;pos+=256){
    int h=pos>>7, w=pos&127;
    const float* Th=T+(h*17)*2;
    float v=Th[0];
    for (int c=1;c<17;c++){
      int p=(c*w)&127;
      v += 2.f*(Th[c*2]*tw[p][0]-Th[c*2+1]*tw[p][1]);
    }
    xp[pos]=v; sum+=v; sq+=v*v;
  }
  block_reduce2(sum,sq);
  float mu=sum*(1.f/NPIX);
  float inv=rsqrtf(sq*(1.f/NPIX)-mu*mu+1e-5f);
  float g=ng[0], bb=nb[0], s_w=sw[0], s_b=sb[0];
  const float* skp = skipsrc + (size_t)bt*NPIX;
  float* op = out + (size_t)bt*NPIX;
  for (int pos=threadIdx.x;pos<NPIX;pos+=256){
    float y = (xp[pos]-mu)*inv*g + bb + skp[pos]*s_w + s_b;
    if (do_gelu) y = 0.5f*y*(1.f + erff(y*0.70710678118f));
    op[pos]=y;
  }
}

// ---- final: out = instance_norm(m2) + attn2 --------------------------------
__global__ __launch_bounds__(256) void k_final(const float* __restrict__ m2, const float* __restrict__ attn2,
                        const float* __restrict__ g, const float* __restrict__ b, float* __restrict__ out){
  int bt=blockIdx.x;
  const float* mp = m2 + (size_t)bt*NPIX;
  const float* ap = attn2 + (size_t)bt*NPIX;
  float* op = out + (size_t)bt*NPIX;
  float sum=0.f,sq=0.f;
  for (int pos=threadIdx.x;pos<NPIX;pos+=256){ float v=mp[pos]; sum+=v; sq+=v*v; }
  block_reduce2(sum,sq);
  float mu=sum*(1.f/NPIX);
  float inv=rsqrtf(sq*(1.f/NPIX)-mu*mu+1e-5f);
  float gg=g[0], bb=b[0];
  for (int pos=threadIdx.x;pos<NPIX;pos+=256)
    op[pos] = (mp[pos]-mu)*inv*gg + bb + ap[pos];
}

extern "C" void kernel_launch(void* const* d_in, const int* in_sizes, int n_in,
                              void* d_out, int out_size, void* d_ws, size_t ws_size,
                              hipStream_t stream){
  const float* x        = (const float*)d_in[0];
  const float* key_w    = (const float*)d_in[1];
  const float* key_sw   = (const float*)d_in[2];
  const float* key_sb   = (const float*)d_in[3];
  const float* query_w  = (const float*)d_in[4];
  const float* query_sw = (const float*)d_in[5];
  const float* query_sb = (const float*)d_in[6];
  const float* value_w  = (const float*)d_in[7];
  const float* value_sw = (const float*)d_in[8];
  const float* value_sb = (const float*)d_in[9];
  const float* proj_w   = (const float*)d_in[10];
  const float* proj_sw  = (const float*)d_in[11];
  const float* proj_sb  = (const float*)d_in[12];
  const float* norm1_g  = (const float*)d_in[13];
  const float* norm1_b  = (const float*)d_in[14];
  const float* attn_g   = (const float*)d_in[15];
  const float* attn_b   = (const float*)d_in[16];
  const float* norm2_g  = (const float*)d_in[17];
  const float* norm2_b  = (const float*)d_in[18];
  const float* mw1      = (const float*)d_in[19];
  const float* msw1     = (const float*)d_in[20];
  const float* msb1     = (const float*)d_in[21];
  const float* mng1     = (const float*)d_in[22];
  const float* mnb1     = (const float*)d_in[23];
  const float* mw2      = (const float*)d_in[24];
  const float* msw2     = (const float*)d_in[25];
  const float* msb2     = (const float*)d_in[26];
  const float* mng2     = (const float*)d_in[27];
  const float* mnb2     = (const float*)d_in[28];
  const float* outg     = (const float*)d_in[29];
  const float* outb     = (const float*)d_in[30];
  float* out = (float*)d_out;
  float* ws  = (float*)d_ws;

  size_t off=0;
  float* tn  = ws + off; off += (size_t)128*16384;     // tokens_norm
  float* A   = ws + off; off += (size_t)128*128*33*2;  // column-DFT temp (max size)
  float* X64 = ws + off; off += (size_t)128*64*33*2;   // 64x33 spectrum of tn
  float* res = ws + off; off += (size_t)128*4096;      // resample64
  float* kb  = ws + off; off += (size_t)128*16*4096;   // K fields
  float* qb  = ws + off; off += (size_t)128*16*4096;   // Q fields
  float* P   = ws + off; off += (size_t)4*16*32*32;    // scores -> softmax P
  float* R   = ws + off; off += (size_t)4*32*32;       // token-mix matrix
  float* XPb = ws + off; off += (size_t)2048*544*2;    // mixed 32x17 spectra per (b,h,t)
  float* Sf  = ws + off; off += (size_t)128*544*2;     // final proj spectrum per token
  float* sk  = ws + off; off += (size_t)128*16384;     // skipmix
  float* a2  = ws + off; off += (size_t)128*16384;     // attn2 (post attn-norm)
  float* m0  = ws + off; off += (size_t)128*16384;
  float* sp  = ws + off; off += (size_t)128*544*2;     // mixer spectrum
  float* xf  = ws + off; off += (size_t)128*16384;     // mixer spectral-field temp
  float* m1  = ws + off; off += (size_t)128*16384;
  float* m2b = ws + off; off += (size_t)128*16384;

  k_norm_x<<<128,256,0,stream>>>(x, norm1_g, norm1_b, tn);
  k_colfft<33><<<512,256,0,stream>>>(tn, A);
  k_rowfft64<<<128,256,0,stream>>>(A, X64);
  k_res64<<<128,256,0,stream>>>(X64, res);
  k_kq<<<dim3(128,16,2),256,0,stream>>>(X64,res, key_w,key_sw,key_sb, query_w,query_sw,query_sb, kb,qb);
  k_scores<<<dim3(4,16),256,0,stream>>>(qb,kb,P);
  k_softmax<<<dim3(64,32),64,0,stream>>>(P);
  k_R<<<dim3(4,32),64,0,stream>>>(P,proj_sw,value_sw,R);
  k_XP<<<dim3(4,16,32),256,0,stream>>>(P,X64,XPb);
  k_Sfin<<<128,256,0,stream>>>(XPb,value_w,value_sw,value_sb,proj_w,proj_sw,Sf);
  k_skipmix<<<dim3(4,32),256,0,stream>>>(tn,R,sk);
  k_proj_final<<<128,256,0,stream>>>(Sf,sk,x,proj_sw,value_sb,proj_sb,attn_g,attn_b,norm2_g,norm2_b,a2,m0);
  k_colfft<17><<<512,256,0,stream>>>(m0,A);
  k_rowfft32<<<128,256,0,stream>>>(A,sp);
  k_mixer<<<128,256,0,stream>>>(sp,mw1,m0,msw1,msb1,mng1,mnb1,xf,m1,1);
  k_colfft<17><<<512,256,0,stream>>>(m1,A);
  k_rowfft32<<<128,256,0,stream>>>(A,sp);
  k_mixer<<<128,256,0,stream>>>(sp,mw2,m1,msw2,msb2,mng2,mnb2,xf,m2b,0);
  k_final<<<128,256,0,stream>>>(m2b,a2,outg,outb,out);
}

// Round 2
// 680.936 us; speedup vs baseline: 1.1879x; 1.1879x over previous
//
#include <hip/hip_runtime.h>
#include <cmath>

#define PI_F 3.14159265358979323846f
#define NTOK 128
#define NPIX 16384
#define NHEADS 16

__device__ __forceinline__ void block_reduce2(float& a, float& b){
  __shared__ float sa[4], sb[4];
  __syncthreads();  // protect sa/sb from a previous call's readers
  for (int o=32;o>0;o>>=1){ a += __shfl_down(a,o); b += __shfl_down(b,o); }
  int w = threadIdx.x>>6, l = threadIdx.x&63;
  if (l==0){ sa[w]=a; sb[w]=b; }
  __syncthreads();
  a = sa[0]+sa[1]+sa[2]+sa[3];
  b = sb[0]+sb[1]+sb[2]+sb[3];
}

__device__ __forceinline__ float block_reduce1(float a){
  __shared__ float sa[4];
  __syncthreads();
  for (int o=32;o>0;o>>=1) a += __shfl_down(a,o);
  int w = threadIdx.x>>6, l = threadIdx.x&63;
  if (l==0) sa[w]=a;
  __syncthreads();
  return sa[0]+sa[1]+sa[2]+sa[3];
}

// ---- Stage 1: instance-norm of x -> tn -------------------------------------
__global__ __launch_bounds__(256) void k_norm_x(const float* __restrict__ x, const float* __restrict__ g,
                         const float* __restrict__ b, float* __restrict__ tn){
  int s = blockIdx.x;
  const float* xs = x + (size_t)s*NPIX;
  float* ts = tn + (size_t)s*NPIX;
  float sum=0.f, sq=0.f;
  for (int i=threadIdx.x;i<NPIX;i+=256){ float v=xs[i]; sum+=v; sq+=v*v; }
  block_reduce2(sum,sq);
  float mu = sum*(1.f/NPIX);
  float var = sq*(1.f/NPIX) - mu*mu;
  float inv = rsqrtf(var + 1e-5f) * g[0];
  float bb = b[0];
  for (int i=threadIdx.x;i<NPIX;i+=256) ts[i] = (xs[i]-mu)*inv + bb;
}

// ---- Column DFT (along w): A[row,c] = sum_w in[row,w] e^{-2pi i c w/128} ---
template<int CMAX>
__global__ __launch_bounds__(256) void k_colfft(const float* __restrict__ in, float* __restrict__ A){
  __shared__ float rows[32*128];
  __shared__ float tw[128][2];
  int base = blockIdx.x*32;  // global row index (token*128 + h)
  for (int i=threadIdx.x;i<32*128;i+=256) rows[i] = in[(size_t)base*128 + i];
  for (int p=threadIdx.x;p<128;p+=256){
    float sn,cs; sincosf(-(2.f*PI_F/128.f)*(float)p, &sn,&cs); tw[p][0]=cs; tw[p][1]=sn;
  }
  __syncthreads();
  for (int e=threadIdx.x; e<32*CMAX; e+=256){
    int r = e/CMAX, c = e%CMAX;
    const float* rp = rows + r*128;
    float re=0.f, im=0.f;
    for (int w=0;w<128;w++){
      int p = (c*w)&127;
      float v = rp[w];
      re += v*tw[p][0]; im += v*tw[p][1];
    }
    float* o = A + ((size_t)(base + r)*CMAX + c)*2;
    o[0]=re; o[1]=im;
  }
}

// ---- Row DFT for 64x33 spectrum (rows 0..31 and 96..127), with 1/16384 -----
// Also emits X64h: the hermitianized (cols 0 and 32) version used for Parseval
// score computation (matches irfft's implicit Im-drop at those columns).
__global__ __launch_bounds__(256) void k_rowfft64(const float* __restrict__ A,
                          float* __restrict__ X64, float* __restrict__ X64h){
  int s = blockIdx.x;
  __shared__ float a[128*33*2];
  __shared__ float S[64*33*2];
  __shared__ float tw[128][2];
  for (int i=threadIdx.x;i<128*33*2;i+=256) a[i] = A[(size_t)s*(128*33*2) + i];
  for (int p=threadIdx.x;p<128;p+=256){ float sn,cs; sincosf(-(2.f*PI_F/128.f)*(float)p,&sn,&cs); tw[p][0]=cs; tw[p][1]=sn; }
  __syncthreads();
  const float sc = 1.f/16384.f;
  for (int e=threadIdx.x;e<64*33;e+=256){
    int i2=e/33, c=e%33;
    int r = (i2<32)? i2 : i2+64;
    float re=0.f, im=0.f;
    for (int h=0;h<128;h++){
      int p=(r*h)&127;
      float cs=tw[p][0], sn=tw[p][1];
      float ar=a[(h*33+c)*2], ai=a[(h*33+c)*2+1];
      re += ar*cs - ai*sn;
      im += ar*sn + ai*cs;
    }
    S[e*2]=re*sc; S[e*2+1]=im*sc;
  }
  __syncthreads();
  for (int e=threadIdx.x;e<64*33;e+=256){
    int r=e/33, c=e%33;
    float vr=S[e*2], vi=S[e*2+1];
    float* o = X64 + ((size_t)s*(64*33) + e)*2;
    o[0]=vr; o[1]=vi;
    float hr=vr, hi=vi;
    if (c==0 || c==32){
      int p = ((64-r)&63)*33 + c;
      hr = 0.5f*(vr + S[p*2]);
      hi = 0.5f*(vi - S[p*2+1]);
    }
    float* oh = X64h + ((size_t)s*(64*33) + e)*2;
    oh[0]=hr; oh[1]=hi;
  }
}

// ---- Z vectors: per (token,head) 17x9-mode effective q/k spectra -----------
// Support rows (64-grid): 0..8 and 56..63 (row 8 catches the col-0 hermitian
// leak from row 56). Zq = aq*X64h + herm(Wq (.) X64raw); Zk likewise, with the
// Parseval column weight w(c) (1 at c=0, else 2) folded into Zk.
__global__ __launch_bounds__(256) void k_Z(const float* __restrict__ X64, const float* __restrict__ X64h,
                    const float* __restrict__ qw, const float* __restrict__ qsw,
                    const float* __restrict__ kw, const float* __restrict__ ksw,
                    float* __restrict__ Zq, float* __restrict__ Zk){
  int t = blockIdx.x;
  __shared__ float2 xr[153], xh[153];
  for (int i=threadIdx.x;i<306;i+=256){
    int side=i/153, m=i%153;
    int j=m/9, c=m%9;
    int r = (j<=8)? j : j+47;
    const float* src = (side? X64h : X64) + ((size_t)t*(64*33) + r*33 + c)*2;
    float2 v; v.x=src[0]; v.y=src[1];
    if (side) xh[m]=v; else xr[m]=v;
  }
  __syncthreads();
  for (int h=0;h<16;h++){
    float aq=qsw[h], ak=ksw[h];
    for (int e=threadIdx.x;e<306;e+=256){
      int side=e/153, m=e%153;
      int j=m/9, c=m%9;
      const float* W = side? kw : qw;
      float a = side? ak : aq;
      float2 pr; pr.x=0.f; pr.y=0.f;
      if (j!=8){
        int jw=(j<8)? j : j-1;
        const float* wp = W + ((size_t)(h*16+jw)*9 + c)*2;
        float2 x = xr[m];
        pr.x = wp[0]*x.x - wp[1]*x.y;
        pr.y = wp[0]*x.y + wp[1]*x.x;
      }
      float2 V = pr;
      if (c==0){
        int jp = (j==0)? 0 : 17-j;
        float2 pp; pp.x=0.f; pp.y=0.f;
        if (jp!=8){
          int jw2=(jp<8)? jp : jp-1;
          const float* wp2 = W + ((size_t)(h*16+jw2)*9 + 0)*2;
          float2 x2 = xr[jp*9];
          pp.x = wp2[0]*x2.x - wp2[1]*x2.y;
          pp.y = wp2[0]*x2.y + wp2[1]*x2.x;
        }
        V.x = 0.5f*(pr.x + pp.x);
        V.y = 0.5f*(pr.y - pp.y);
      }
      float2 xm = xh[m];
      float zr = a*xm.x + V.x;
      float zi = a*xm.y + V.y;
      float wf = (side && c!=0)? 2.f : 1.f;
      float* dst = (side? Zk : Zq) + ((size_t)(t*16+h))*306 + m*2;
      dst[0]=wf*zr; dst[1]=wf*zi;
    }
  }
}

// ---- Ue[b,t,s]: head-independent gram over the complementary 1959 modes ----
__global__ __launch_bounds__(256) void k_Ue(const float* __restrict__ X64h, float* __restrict__ Ue){
  int b=blockIdx.x, t=blockIdx.y;
  __shared__ float wt[2112];
  __shared__ float2 xt[2112];
  __shared__ float2 xs[2112];
  for (int m=threadIdx.x;m<2112;m+=256){
    int r=m/33, c=m%33;
    bool excl = (c<=8) && (r<=8 || r>=56);
    wt[m] = excl? 0.f : ((c==0||c==32)? 1.f : 2.f);
  }
  __syncthreads();
  const float2* src = (const float2*)(X64h + ((size_t)(b*32+t))*(64*33)*2);
  for (int m=threadIdx.x;m<2112;m+=256){
    float2 v = src[m];
    float w = wt[m];
    v.x*=w; v.y*=w;
    xt[m]=v;
  }
  for (int s=0;s<32;s++){
    __syncthreads();
    const float2* ss = (const float2*)(X64h + ((size_t)(b*32+s))*(64*33)*2);
    for (int m=threadIdx.x;m<2112;m+=256) xs[m]=ss[m];
    __syncthreads();
    float acc=0.f;
    for (int m=threadIdx.x;m<2112;m+=256){
      float2 a2=xt[m], b2=xs[m];
      acc += a2.x*b2.x + a2.y*b2.y;
    }
    float r = block_reduce1(acc);
    if (threadIdx.x==0) Ue[((size_t)(b*32+t))*32 + s] = r;
  }
}

// ---- scores + softmax: P[b,h,t,s] -----------------------------------------
__global__ __launch_bounds__(256) void k_scores2(const float* __restrict__ Zq, const float* __restrict__ Zk,
                          const float* __restrict__ Ue,
                          const float* __restrict__ qsw, const float* __restrict__ qsb,
                          const float* __restrict__ ksw, const float* __restrict__ ksb,
                          float* __restrict__ P){
  int b=blockIdx.x, h=blockIdx.y;
  __shared__ float2 zq[32][154];
  __shared__ float2 zk[16][154];
  __shared__ float Pl[32][33];
  for (int i=threadIdx.x;i<32*153;i+=256){
    int t=i/153, m=i%153;
    const float2* src=(const float2*)(Zq + ((size_t)((b*32+t)*16+h))*306);
    zq[t][m]=src[m];
  }
  float aq=qsw[h], ak=ksw[h], bq=qsb[h], bk=ksb[h];
  float aqak=aq*ak;
  int t=threadIdx.x>>3, sl=threadIdx.x&7;
  for (int ch=0; ch<2; ch++){
    __syncthreads();
    for (int i=threadIdx.x;i<16*153;i+=256){
      int s=i/153, m=i%153;
      const float2* src=(const float2*)(Zk + ((size_t)((b*32+ch*16+s)*16+h))*306);
      zk[s][m]=src[m];
    }
    __syncthreads();
    for (int u=0;u<2;u++){
      int sr = sl + u*8;
      int s = ch*16 + sr;
      float acc=0.f;
      for (int m=0;m<153;m++){
        float2 a2=zq[t][m], c2=zk[sr][m];
        acc += a2.x*c2.x + a2.y*c2.y;
      }
      float G = aqak*Ue[((size_t)(b*32+t))*32+s] + acc;
      Pl[t][s] = 64.f*(G + bk*zq[t][0].x + bq*zk[sr][0].x + bq*bk);
    }
  }
  __syncthreads();
  if (threadIdx.x<32){
    int tt=threadIdx.x;
    float mx=-INFINITY;
    for (int s=0;s<32;s++) mx=fmaxf(mx,Pl[tt][s]);
    float e[32]; float sum=0.f;
    for (int s=0;s<32;s++){ e[s]=expf(Pl[tt][s]-mx); sum+=e[s]; }
    float inv=1.f/sum;
    size_t base=((size_t)(b*16+h)*32+tt)*32;
    for (int s=0;s<32;s++) P[base+s]=e[s]*inv;
  }
}

// ---- R[b,t,s] = sum_h pw[h]*vw[h]*P[b,h,t,s] -------------------------------
__global__ __launch_bounds__(64) void k_R(const float* __restrict__ P, const float* __restrict__ pw,
                    const float* __restrict__ vw, float* __restrict__ R){
  int b=blockIdx.x, t=blockIdx.y;
  int s2=threadIdx.x;
  if (s2<32){
    float acc=0.f;
    for (int h=0;h<16;h++)
      acc += pw[h]*vw[h]*P[(((size_t)(b*16+h)*32)+t)*32 + s2];
    R[((size_t)(b*32+t))*32 + s2] = acc;
  }
}

// ---- XP[b,h,t] = sum_s P[b,h,t,s] * X32(token b,s)  (32x17 modes) ----------
__global__ __launch_bounds__(256) void k_XP(const float* __restrict__ P, const float* __restrict__ X64, float* __restrict__ XP){
  int b=blockIdx.x, h=blockIdx.y, t=blockIdx.z;
  __shared__ float Pr[32];
  if (threadIdx.x<32) Pr[threadIdx.x] = P[(((size_t)(b*16+h)*32)+t)*32 + threadIdx.x];
  __syncthreads();
  size_t obase = ((size_t)((b*16+h)*32+t))*544;
  for (int e=threadIdx.x;e<544;e+=256){
    int j=e/17, c=e%17;
    int i2 = (j<16)? j : (j+32);   // X64 storage rows: 0..15 and 48..63 (Xft 112..127)
    float re=0.f, im=0.f;
    for (int s2=0;s2<32;s2++){
      const float* xp = X64 + (((size_t)(b*32+s2))*(64*33) + i2*33 + c)*2;
      float p = Pr[s2];
      re += p*xp[0]; im += p*xp[1];
    }
    XP[(obase+e)*2]=re; XP[(obase+e)*2+1]=im;
  }
}

// ---- final per-token proj spectrum (32x17) with hermitian-c0 projection ----
__global__ __launch_bounds__(256) void k_Sfin(const float* __restrict__ XP,
                       const float* __restrict__ value_w, const float* __restrict__ vsw, const float* __restrict__ vsb,
                       const float* __restrict__ proj_w, const float* __restrict__ psw,
                       float* __restrict__ Sfin){
  int bt=blockIdx.x; int b=bt>>5, t=bt&31;
  __shared__ float XPs[544*2];
  float ar[3]={0,0,0}, ai[3]={0,0,0};
  for (int h=0;h<16;h++){
    __syncthreads();
    const float* src = XP + (((size_t)((b*16+h)*32+t))*544)*2;
    for (int i=threadIdx.x;i<1088;i+=256) XPs[i]=src[i];
    __syncthreads();
    float vw = vsw[h], vb = vsb[h], pw = psw[h];
    for (int u=0;u<3;u++){
      int e = threadIdx.x + u*256;
      if (e>=544) break;
      int j=e/17, c=e%17;
      float xr=XPs[e*2], xi=XPs[e*2+1];
      float wvr=0.f, wvi=0.f;
      if (c<=8 && (j<8 || j>=24)){                 // v-mode support
        int jw = (j<8)? j : (j-16);                // value_w row
        const float* wv = value_w + ((size_t)(h*16+jw)*9 + c)*2;
        wvr=wv[0]; wvi=wv[1];
      }
      float Mr = xr*wvr - xi*wvi;                  // M = XP * Wv
      float Mi = xr*wvi + xi*wvr;
      float Mhr=Mr, Mhi=Mi;
      if (c==0){                                   // hermitian projection at col 0
        float Pr2=0.f, Pi2=0.f;
        int jp2 = (j==0)? 0 : ((j==16)? -1 : 32-j);
        if (jp2>=0 && (jp2<8 || jp2>=24)){
          int jw2 = (jp2<8)? jp2 : (jp2-16);
          const float* wv2 = value_w + ((size_t)(h*16+jw2)*9)*2;
          float pxr=XPs[(jp2*17)*2], pxi=XPs[(jp2*17)*2+1];
          Pr2 = pxr*wv2[0] - pxi*wv2[1];
          Pi2 = pxr*wv2[1] + pxi*wv2[0];
        }
        Mhr = 0.5f*(Mr + Pr2);
        Mhi = 0.5f*(Mi - Pi2);
      }
      float Yr = vw*xr + Mhr + ((e==0)? vb : 0.f); // rfft2(attn[h]) on proj support
      float Yi = vw*xi + Mhi;
      const float* pc = proj_w + ((size_t)(h*32+j)*17 + c)*2;
      float pr=pc[0], pi=pc[1];
      ar[u] += pr*Yr - pi*Yi + pw*Mr;              // + pw*Mv (skip path, folded)
      ai[u] += pr*Yi + pi*Yr + pw*Mi;
    }
  }
  for (int u=0;u<3;u++){
    int e = threadIdx.x + u*256;
    if (e<544){ Sfin[((size_t)bt*544+e)*2]=ar[u]; Sfin[((size_t)bt*544+e)*2+1]=ai[u]; }
  }
}

// ---- skipmix[b,t,:] = sum_s R[b,t,s]*tn[b,s,:] -----------------------------
__global__ __launch_bounds__(256) void k_skipmix(const float* __restrict__ tn, const float* __restrict__ R, float* __restrict__ out){
  int b=blockIdx.x, ch=blockIdx.y;
  int base = ch*512;
  __shared__ float Rs[32][32];
  for (int i=threadIdx.x;i<1024;i+=256) Rs[i>>5][i&31] = R[(size_t)b*1024 + i];
  __syncthreads();
  float a0[32], a1[32];
  #pragma unroll
  for (int t2=0;t2<32;t2++){ a0[t2]=0.f; a1[t2]=0.f; }
  for (int s2=0;s2<32;s2++){
    const float* tp = tn + ((size_t)(b*32+s2))*NPIX + base;
    float v0 = tp[threadIdx.x], v1 = tp[threadIdx.x+256];
    #pragma unroll
    for (int t2=0;t2<32;t2++){ float r=Rs[t2][s2]; a0[t2]+=r*v0; a1[t2]+=r*v1; }
  }
  #pragma unroll
  for (int t2=0;t2<32;t2++){
    float* op = out + ((size_t)(b*32+t2))*NPIX + base;
    op[threadIdx.x]=a0[t2]; op[threadIdx.x+256]=a1[t2];
  }
}

// ---- proj finalize: irfft128 + skip + residual + 2 instance norms ----------
__global__ __launch_bounds__(256) void k_proj_final(const float* __restrict__ Sfin, const float* __restrict__ skipmix,
                             const float* __restrict__ x,
                             const float* __restrict__ psw, const float* __restrict__ vsb, const float* __restrict__ psb,
                             const float* __restrict__ ag, const float* __restrict__ ab,
                             const float* __restrict__ n2g, const float* __restrict__ n2b,
                             float* __restrict__ attn2, float* __restrict__ m0){
  int bt=blockIdx.x;
  __shared__ float Ss[544*2];
  __shared__ float T[128*17*2];
  __shared__ float tw[128][2];
  for (int i=threadIdx.x;i<1088;i+=256) Ss[i] = Sfin[(size_t)bt*1088 + i];
  for (int p=threadIdx.x;p<128;p+=256){ float sn,cs; sincosf((2.f*PI_F/128.f)*(float)p,&sn,&cs); tw[p][0]=cs; tw[p][1]=sn; }
  __syncthreads();
  for (int e=threadIdx.x;e<128*17;e+=256){
    int h=e/17, c=e%17;
    float re=0.f, im=0.f;
    for (int j=0;j<32;j++){
      int r = (j<16)? j : (j+96);
      int p=(r*h)&127;
      float cs=tw[p][0], sn=tw[p][1];
      float arv=Ss[(j*17+c)*2], aiv=Ss[(j*17+c)*2+1];
      re += arv*cs - aiv*sn;
      im += arv*sn + aiv*cs;
    }
    T[e*2]=re; T[e*2+1]=im;
  }
  __syncthreads();
  float Cb = psb[0];
  for (int h=0;h<16;h++) Cb += psw[h]*vsb[h];
  float sum=0.f,sq=0.f;
  float* zb = attn2 + (size_t)bt*NPIX;
  const float* sm = skipmix + (size_t)bt*NPIX;
  const float* xs = x + (size_t)bt*NPIX;
  for (int pos=threadIdx.x;pos<NPIX;pos+=256){
    int h=pos>>7, w=pos&127;
    const float* Th = T + (h*17)*2;
    float v = Th[0];
    for (int c=1;c<17;c++){
      int p=(c*w)&127;
      v += 2.f*(Th[c*2]*tw[p][0] - Th[c*2+1]*tw[p][1]);
    }
    v += sm[pos] + Cb + xs[pos];
    zb[pos]=v; sum+=v; sq+=v*v;
  }
  block_reduce2(sum,sq);
  float mu = sum*(1.f/NPIX);
  float inv = rsqrtf(sq*(1.f/NPIX)-mu*mu + 1e-5f);
  float g1=ag[0], b1=ab[0];
  float sum2=0.f,sq2=0.f;
  for (int pos=threadIdx.x;pos<NPIX;pos+=256){
    float a = (zb[pos]-mu)*inv*g1 + b1;
    zb[pos]=a; sum2+=a; sq2+=a*a;
  }
  block_reduce2(sum2,sq2);
  float mu2 = sum2*(1.f/NPIX);
  float inv2 = rsqrtf(sq2*(1.f/NPIX)-mu2*mu2 + 1e-5f);
  float g2=n2g[0], b2=n2b[0];
  float* m0p = m0 + (size_t)bt*NPIX;
  for (int pos=threadIdx.x;pos<NPIX;pos+=256)
    m0p[pos] = (zb[pos]-mu2)*inv2*g2 + b2;
}

// ---- forward 32x17 modes (rows 0..15, 112..127) for mixer ------------------
__global__ __launch_bounds__(256) void k_rowfft32(const float* __restrict__ A, float* __restrict__ spec){
  int s=blockIdx.x;
  __shared__ float a[128*17*2];
  __shared__ float tw[128][2];
  for (int i=threadIdx.x;i<128*17*2;i+=256) a[i]=A[(size_t)s*(128*17*2)+i];
  for (int p=threadIdx.x;p<128;p+=256){ float sn,cs; sincosf(-(2.f*PI_F/128.f)*(float)p,&sn,&cs); tw[p][0]=cs; tw[p][1]=sn; }
  __syncthreads();
  const float sc=1.f/16384.f;
  for (int e=threadIdx.x;e<544;e+=256){
    int j=e/17, c=e%17;
    int r=(j<16)? j : (j+96);
    float re=0.f,im=0.f;
    for (int h=0;h<128;h++){
      int p=(r*h)&127;
      float cs=tw[p][0], sn=tw[p][1];
      float ar=a[(h*17+c)*2], ai=a[(h*17+c)*2+1];
      re += ar*cs - ai*sn;
      im += ar*sn + ai*cs;
    }
    spec[((size_t)s*544+e)*2]=re*sc; spec[((size_t)s*544+e)*2+1]=im*sc;
  }
}

// ---- one mixer FNO layer: irfft(spec*w) -> inst-norm -> +skip -> (gelu) ----
__global__ __launch_bounds__(256) void k_mixer(const float* __restrict__ spec, const float* __restrict__ wm,
                        const float* __restrict__ skipsrc, const float* __restrict__ sw, const float* __restrict__ sb,
                        const float* __restrict__ ng, const float* __restrict__ nb,
                        float* __restrict__ xfb, float* __restrict__ out, int do_gelu){
  int bt=blockIdx.x;
  __shared__ float Ss[544*2];
  __shared__ float T[128*17*2];
  __shared__ float tw[128][2];
  for (int e=threadIdx.x;e<544;e+=256){
    float xr=spec[((size_t)bt*544+e)*2], xi=spec[((size_t)bt*544+e)*2+1];
    float wr=wm[e*2], wi=wm[e*2+1];
    Ss[e*2]=xr*wr-xi*wi; Ss[e*2+1]=xr*wi+xi*wr;
  }
  for (int p=threadIdx.x;p<128;p+=256){ float sn,cs; sincosf((2.f*PI_F/128.f)*(float)p,&sn,&cs); tw[p][0]=cs; tw[p][1]=sn; }
  __syncthreads();
  for (int e=threadIdx.x;e<128*17;e+=256){
    int h=e/17, c=e%17;
    float re=0.f,im=0.f;
    for (int j=0;j<32;j++){
      int r=(j<16)? j:(j+96);
      int p=(r*h)&127;
      float cs=tw[p][0], sn=tw[p][1];
      float ar=Ss[(j*17+c)*2], ai=Ss[(j*17+c)*2+1];
      re += ar*cs-ai*sn; im += ar*sn+ai*cs;
    }
    T[e*2]=re; T[e*2+1]=im;
  }
  __syncthreads();
  float sum=0.f,sq=0.f;
  float* xp = xfb + (size_t)bt*NPIX;
  for (int pos=threadIdx.x;pos<NPIX;pos+=256){
    int h=pos>>7, w=pos&127;
    const float* Th=T+(h*17)*2;
    float v=Th[0];
    for (int c=1;c<17;c++){
      int p=(c*w)&127;
      v += 2.f*(Th[c*2]*tw[p][0]-Th[c*2+1]*tw[p][1]);
    }
    xp[pos]=v; sum+=v; sq+=v*v;
  }
  block_reduce2(sum,sq);
  float mu=sum*(1.f/NPIX);
  float inv=rsqrtf(sq*(1.f/NPIX)-mu*mu+1e-5f);
  float g=ng[0], bb=nb[0], s_w=sw[0], s_b=sb[0];
  const float* skp = skipsrc + (size_t)bt*NPIX;
  float* op = out + (size_t)bt*NPIX;
  for (int pos=threadIdx.x;pos<NPIX;pos+=256){
    float y = (xp[pos]-mu)*inv*g + bb + skp[pos]*s_w + s_b;
    if (do_gelu) y = 0.5f*y*(1.f + erff(y*0.70710678118f));
    op[pos]=y;
  }
}

// ---- final: out = instance_norm(m2) + attn2 --------------------------------
__global__ __launch_bounds__(256) void k_final(const float* __restrict__ m2, const float* __restrict__ attn2,
                        const float* __restrict__ g, const float* __restrict__ b, float* __restrict__ out){
  int bt=blockIdx.x;
  const float* mp = m2 + (size_t)bt*NPIX;
  const float* ap = attn2 + (size_t)bt*NPIX;
  float* op = out + (size_t)bt*NPIX;
  float sum=0.f,sq=0.f;
  for (int pos=threadIdx.x;pos<NPIX;pos+=256){ float v=mp[pos]; sum+=v; sq+=v*v; }
  block_reduce2(sum,sq);
  float mu=sum*(1.f/NPIX);
  float inv=rsqrtf(sq*(1.f/NPIX)-mu*mu+1e-5f);
  float gg=g[0], bb=b[0];
  for (int pos=threadIdx.x;pos<NPIX;pos+=256)
    op[pos] = (mp[pos]-mu)*inv*gg + bb + ap[pos];
}

extern "C" void kernel_launch(void* const* d_in, const int* in_sizes, int n_in,
                              void* d_out, int out_size, void* d_ws, size_t ws_size,
                              hipStream_t stream){
  const float* x        = (const float*)d_in[0];
  const float* key_w    = (const float*)d_in[1];
  const float* key_sw   = (const float*)d_in[2];
  const float* key_sb   = (const float*)d_in[3];
  const float* query_w  = (const float*)d_in[4];
  const float* query_sw = (const float*)d_in[5];
  const float* query_sb = (const float*)d_in[6];
  const float* value_w  = (const float*)d_in[7];
  const float* value_sw = (const float*)d_in[8];
  const float* value_sb = (const float*)d_in[9];
  const float* proj_w   = (const float*)d_in[10];
  const float* proj_sw  = (const float*)d_in[11];
  const float* proj_sb  = (const float*)d_in[12];
  const float* norm1_g  = (const float*)d_in[13];
  const float* norm1_b  = (const float*)d_in[14];
  const float* attn_g   = (const float*)d_in[15];
  const float* attn_b   = (const float*)d_in[16];
  const float* norm2_g  = (const float*)d_in[17];
  const float* norm2_b  = (const float*)d_in[18];
  const float* mw1      = (const float*)d_in[19];
  const float* msw1     = (const float*)d_in[20];
  const float* msb1     = (const float*)d_in[21];
  const float* mng1     = (const float*)d_in[22];
  const float* mnb1     = (const float*)d_in[23];
  const float* mw2      = (const float*)d_in[24];
  const float* msw2     = (const float*)d_in[25];
  const float* msb2     = (const float*)d_in[26];
  const float* mng2     = (const float*)d_in[27];
  const float* mnb2     = (const float*)d_in[28];
  const float* outg     = (const float*)d_in[29];
  const float* outb     = (const float*)d_in[30];
  float* out = (float*)d_out;
  float* ws  = (float*)d_ws;

  size_t off=0;
  float* tn  = ws + off; off += (size_t)128*16384;     // tokens_norm
  float* A   = ws + off; off += (size_t)128*128*33*2;  // column-DFT temp (max size)
  float* X64 = ws + off; off += (size_t)128*64*33*2;   // 64x33 spectrum of tn (raw)
  float* X64h= ws + off; off += (size_t)128*64*33*2;   // hermitianized (cols 0,32)
  float* Zq  = ws + off; off += (size_t)128*16*306;    // per (t,h) q spectra (153 cplx)
  float* Zk  = ws + off; off += (size_t)128*16*306;    // per (t,h) k spectra (w-folded)
  float* Ue  = ws + off; off += (size_t)4*32*32;       // head-indep complementary gram
  float* P   = ws + off; off += (size_t)4*16*32*32;    // softmaxed attention
  float* R   = ws + off; off += (size_t)4*32*32;       // token-mix matrix
  float* XPb = ws + off; off += (size_t)2048*544*2;    // mixed 32x17 spectra per (b,h,t)
  float* Sf  = ws + off; off += (size_t)128*544*2;     // final proj spectrum per token
  float* sk  = ws + off; off += (size_t)128*16384;     // skipmix
  float* a2  = ws + off; off += (size_t)128*16384;     // attn2 (post attn-norm)
  float* m0  = ws + off; off += (size_t)128*16384;
  float* sp  = ws + off; off += (size_t)128*544*2;     // mixer spectrum
  float* xf  = ws + off; off += (size_t)128*16384;     // mixer spectral-field temp
  float* m1  = ws + off; off += (size_t)128*16384;
  float* m2b = ws + off; off += (size_t)128*16384;

  k_norm_x<<<128,256,0,stream>>>(x, norm1_g, norm1_b, tn);
  k_colfft<33><<<512,256,0,stream>>>(tn, A);
  k_rowfft64<<<128,256,0,stream>>>(A, X64, X64h);
  k_Z<<<128,256,0,stream>>>(X64, X64h, query_w, query_sw, key_w, key_sw, Zq, Zk);
  k_Ue<<<dim3(4,32),256,0,stream>>>(X64h, Ue);
  k_scores2<<<dim3(4,16),256,0,stream>>>(Zq, Zk, Ue, query_sw, query_sb, key_sw, key_sb, P);
  k_R<<<dim3(4,32),64,0,stream>>>(P,proj_sw,value_sw,R);
  k_XP<<<dim3(4,16,32),256,0,stream>>>(P,X64,XPb);
  k_Sfin<<<128,256,0,stream>>>(XPb,value_w,value_sw,value_sb,proj_w,proj_sw,Sf);
  k_skipmix<<<dim3(4,32),256,0,stream>>>(tn,R,sk);
  k_proj_final<<<128,256,0,stream>>>(Sf,sk,x,proj_sw,value_sb,proj_sb,attn_g,attn_b,norm2_g,norm2_b,a2,m0);
  k_colfft<17><<<512,256,0,stream>>>(m0,A);
  k_rowfft32<<<128,256,0,stream>>>(A,sp);
  k_mixer<<<128,256,0,stream>>>(sp,mw1,m0,msw1,msb1,mng1,mnb1,xf,m1,1);
  k_colfft<17><<<512,256,0,stream>>>(m1,A);
  k_rowfft32<<<128,256,0,stream>>>(A,sp);
  k_mixer<<<128,256,0,stream>>>(sp,mw2,m1,msw2,msb2,mng2,mnb2,xf,m2b,0);
  k_final<<<128,256,0,stream>>>(m2b,a2,outg,outb,out);
}

// Round 3
// 504.633 us; speedup vs baseline: 1.6029x; 1.3494x over previous
//
#include <hip/hip_runtime.h>
#include <cmath>

#define PI_F 3.14159265358979323846f
#define NTOK 128
#define NPIX 16384
#define NHEADS 16

__device__ __forceinline__ void block_reduce2(float& a, float& b){
  __shared__ float sa[4], sb[4];
  __syncthreads();  // protect sa/sb from a previous call's readers
  for (int o=32;o>0;o>>=1){ a += __shfl_down(a,o); b += __shfl_down(b,o); }
  int w = threadIdx.x>>6, l = threadIdx.x&63;
  if (l==0){ sa[w]=a; sb[w]=b; }
  __syncthreads();
  a = sa[0]+sa[1]+sa[2]+sa[3];
  b = sb[0]+sb[1]+sb[2]+sb[3];
}

__device__ __forceinline__ float block_reduce1(float a){
  __shared__ float sa[4];
  __syncthreads();
  for (int o=32;o>0;o>>=1) a += __shfl_down(a,o);
  int w = threadIdx.x>>6, l = threadIdx.x&63;
  if (l==0) sa[w]=a;
  __syncthreads();
  return sa[0]+sa[1]+sa[2]+sa[3];
}

__device__ __forceinline__ float gelu_f(float y){
  return 0.5f*y*(1.f + erff(y*0.70710678118f));
}

// ---- Stage 1: instance-norm of x -> tn -------------------------------------
__global__ __launch_bounds__(256) void k_norm_x(const float* __restrict__ x, const float* __restrict__ g,
                         const float* __restrict__ b, float* __restrict__ tn){
  int s = blockIdx.x;
  const float* xs = x + (size_t)s*NPIX;
  float* ts = tn + (size_t)s*NPIX;
  float sum=0.f, sq=0.f;
  for (int i=threadIdx.x;i<NPIX;i+=256){ float v=xs[i]; sum+=v; sq+=v*v; }
  block_reduce2(sum,sq);
  float mu = sum*(1.f/NPIX);
  float var = sq*(1.f/NPIX) - mu*mu;
  float inv = rsqrtf(var + 1e-5f) * g[0];
  float bb = b[0];
  for (int i=threadIdx.x;i<NPIX;i+=256) ts[i] = (xs[i]-mu)*inv + bb;
}

// ---- Column DFT (along w): A[row,c] = sum_w in[row,w] e^{-2pi i c w/128} ---
template<int CMAX>
__global__ __launch_bounds__(256) void k_colfft(const float* __restrict__ in, float* __restrict__ A){
  __shared__ float rows[32*128];
  __shared__ float tw[128][2];
  int base = blockIdx.x*32;  // global row index (token*128 + h)
  for (int i=threadIdx.x;i<32*128;i+=256) rows[i] = in[(size_t)base*128 + i];
  for (int p=threadIdx.x;p<128;p+=256){
    float sn,cs; sincosf(-(2.f*PI_F/128.f)*(float)p, &sn,&cs); tw[p][0]=cs; tw[p][1]=sn;
  }
  __syncthreads();
  for (int e=threadIdx.x; e<32*CMAX; e+=256){
    int r = e/CMAX, c = e%CMAX;
    const float* rp = rows + r*128;
    float sn,cs; sincosf(-(2.f*PI_F/128.f)*(float)c,&sn,&cs);
    float rr=1.f, ri=0.f, re=0.f, im=0.f;
    for (int w=0;w<128;w++){
      float v = rp[w];
      re += v*rr; im += v*ri;
      float nr = rr*cs - ri*sn; ri = rr*sn + ri*cs; rr = nr;
    }
    float* o = A + ((size_t)(base + r)*CMAX + c)*2;
    o[0]=re; o[1]=im;
  }
}

// ---- Row DFT for 64x33 spectrum (rows 0..31 and 96..127), with 1/16384 -----
// Also emits X64h: hermitianized (cols 0 and 32) version for Parseval scores.
__global__ __launch_bounds__(256) void k_rowfft64(const float* __restrict__ A,
                          float* __restrict__ X64, float* __restrict__ X64h){
  int s = blockIdx.x;
  __shared__ float a[128*33*2];
  __shared__ float S[64*33*2];
  __shared__ float tw[128][2];
  for (int i=threadIdx.x;i<128*33*2;i+=256) a[i] = A[(size_t)s*(128*33*2) + i];
  for (int p=threadIdx.x;p<128;p+=256){ float sn,cs; sincosf(-(2.f*PI_F/128.f)*(float)p,&sn,&cs); tw[p][0]=cs; tw[p][1]=sn; }
  __syncthreads();
  const float sc = 1.f/16384.f;
  for (int e=threadIdx.x;e<64*33;e+=256){
    int i2=e/33, c=e%33;
    int r = (i2<32)? i2 : i2+64;
    float re=0.f, im=0.f;
    for (int h=0;h<128;h++){
      int p=(r*h)&127;
      float cs=tw[p][0], sn=tw[p][1];
      float ar=a[(h*33+c)*2], ai=a[(h*33+c)*2+1];
      re += ar*cs - ai*sn;
      im += ar*sn + ai*cs;
    }
    S[e*2]=re*sc; S[e*2+1]=im*sc;
  }
  __syncthreads();
  for (int e=threadIdx.x;e<64*33;e+=256){
    int r=e/33, c=e%33;
    float vr=S[e*2], vi=S[e*2+1];
    float* o = X64 + ((size_t)s*(64*33) + e)*2;
    o[0]=vr; o[1]=vi;
    float hr=vr, hi=vi;
    if (c==0 || c==32){
      int p = ((64-r)&63)*33 + c;
      hr = 0.5f*(vr + S[p*2]);
      hi = 0.5f*(vi - S[p*2+1]);
    }
    float* oh = X64h + ((size_t)s*(64*33) + e)*2;
    oh[0]=hr; oh[1]=hi;
  }
}

// ---- Z vectors: per (token,head) 17x9-mode effective q/k spectra -----------
__global__ __launch_bounds__(256) void k_Z(const float* __restrict__ X64, const float* __restrict__ X64h,
                    const float* __restrict__ qw, const float* __restrict__ qsw,
                    const float* __restrict__ kw, const float* __restrict__ ksw,
                    float* __restrict__ Zq, float* __restrict__ Zk){
  int t = blockIdx.x;
  __shared__ float2 xr[153], xh[153];
  for (int i=threadIdx.x;i<306;i+=256){
    int side=i/153, m=i%153;
    int j=m/9, c=m%9;
    int r = (j<=8)? j : j+47;
    const float* src = (side? X64h : X64) + ((size_t)t*(64*33) + r*33 + c)*2;
    float2 v; v.x=src[0]; v.y=src[1];
    if (side) xh[m]=v; else xr[m]=v;
  }
  __syncthreads();
  for (int h=0;h<16;h++){
    float aq=qsw[h], ak=ksw[h];
    for (int e=threadIdx.x;e<306;e+=256){
      int side=e/153, m=e%153;
      int j=m/9, c=m%9;
      const float* W = side? kw : qw;
      float a = side? ak : aq;
      float2 pr; pr.x=0.f; pr.y=0.f;
      if (j!=8){
        int jw=(j<8)? j : j-1;
        const float* wp = W + ((size_t)(h*16+jw)*9 + c)*2;
        float2 x = xr[m];
        pr.x = wp[0]*x.x - wp[1]*x.y;
        pr.y = wp[0]*x.y + wp[1]*x.x;
      }
      float2 V = pr;
      if (c==0){
        int jp = (j==0)? 0 : 17-j;
        float2 pp; pp.x=0.f; pp.y=0.f;
        if (jp!=8){
          int jw2=(jp<8)? jp : jp-1;
          const float* wp2 = W + ((size_t)(h*16+jw2)*9 + 0)*2;
          float2 x2 = xr[jp*9];
          pp.x = wp2[0]*x2.x - wp2[1]*x2.y;
          pp.y = wp2[0]*x2.y + wp2[1]*x2.x;
        }
        V.x = 0.5f*(pr.x + pp.x);
        V.y = 0.5f*(pr.y - pp.y);
      }
      float2 xm = xh[m];
      float zr = a*xm.x + V.x;
      float zi = a*xm.y + V.y;
      float wf = (side && c!=0)? 2.f : 1.f;
      float* dst = (side? Zk : Zq) + ((size_t)(t*16+h))*306 + m*2;
      dst[0]=wf*zr; dst[1]=wf*zi;
    }
  }
}

// ---- Ue[b,t,s]: head-independent gram over the complementary modes ---------
__global__ __launch_bounds__(256) void k_Ue(const float* __restrict__ X64h, float* __restrict__ Ue){
  int b=blockIdx.x, t=blockIdx.y;
  __shared__ float wt[2112];
  __shared__ float2 xt[2112];
  __shared__ float2 xs[2112];
  for (int m=threadIdx.x;m<2112;m+=256){
    int r=m/33, c=m%33;
    bool excl = (c<=8) && (r<=8 || r>=56);
    wt[m] = excl? 0.f : ((c==0||c==32)? 1.f : 2.f);
  }
  __syncthreads();
  const float2* src = (const float2*)(X64h + ((size_t)(b*32+t))*(64*33)*2);
  for (int m=threadIdx.x;m<2112;m+=256){
    float2 v = src[m];
    float w = wt[m];
    v.x*=w; v.y*=w;
    xt[m]=v;
  }
  for (int s=0;s<32;s++){
    __syncthreads();
    const float2* ss = (const float2*)(X64h + ((size_t)(b*32+s))*(64*33)*2);
    for (int m=threadIdx.x;m<2112;m+=256) xs[m]=ss[m];
    __syncthreads();
    float acc=0.f;
    for (int m=threadIdx.x;m<2112;m+=256){
      float2 a2=xt[m], b2=xs[m];
      acc += a2.x*b2.x + a2.y*b2.y;
    }
    float r = block_reduce1(acc);
    if (threadIdx.x==0) Ue[((size_t)(b*32+t))*32 + s] = r;
  }
}

// ---- scores + softmax: P[b,h,t,s] -----------------------------------------
__global__ __launch_bounds__(256) void k_scores2(const float* __restrict__ Zq, const float* __restrict__ Zk,
                          const float* __restrict__ Ue,
                          const float* __restrict__ qsw, const float* __restrict__ qsb,
                          const float* __restrict__ ksw, const float* __restrict__ ksb,
                          float* __restrict__ P){
  int b=blockIdx.x, h=blockIdx.y;
  __shared__ float2 zq[32][154];
  __shared__ float2 zk[16][154];
  __shared__ float Pl[32][33];
  for (int i=threadIdx.x;i<32*153;i+=256){
    int t=i/153, m=i%153;
    const float2* src=(const float2*)(Zq + ((size_t)((b*32+t)*16+h))*306);
    zq[t][m]=src[m];
  }
  float aq=qsw[h], ak=ksw[h], bq=qsb[h], bk=ksb[h];
  float aqak=aq*ak;
  int t=threadIdx.x>>3, sl=threadIdx.x&7;
  for (int ch=0; ch<2; ch++){
    __syncthreads();
    for (int i=threadIdx.x;i<16*153;i+=256){
      int s=i/153, m=i%153;
      const float2* src=(const float2*)(Zk + ((size_t)((b*32+ch*16+s)*16+h))*306);
      zk[s][m]=src[m];
    }
    __syncthreads();
    for (int u=0;u<2;u++){
      int sr = sl + u*8;
      int s = ch*16 + sr;
      float acc=0.f;
      for (int m=0;m<153;m++){
        float2 a2=zq[t][m], c2=zk[sr][m];
        acc += a2.x*c2.x + a2.y*c2.y;
      }
      float G = aqak*Ue[((size_t)(b*32+t))*32+s] + acc;
      Pl[t][s] = 64.f*(G + bk*zq[t][0].x + bq*zk[sr][0].x + bq*bk);
    }
  }
  __syncthreads();
  if (threadIdx.x<32){
    int tt=threadIdx.x;
    float mx=-INFINITY;
    for (int s=0;s<32;s++) mx=fmaxf(mx,Pl[tt][s]);
    float e[32]; float sum=0.f;
    for (int s=0;s<32;s++){ e[s]=expf(Pl[tt][s]-mx); sum+=e[s]; }
    float inv=1.f/sum;
    size_t base=((size_t)(b*16+h)*32+tt)*32;
    for (int s=0;s<32;s++) P[base+s]=e[s]*inv;
  }
}

// ---- R[b,t,s] = sum_h pw[h]*vw[h]*P[b,h,t,s] -------------------------------
__global__ __launch_bounds__(64) void k_R(const float* __restrict__ P, const float* __restrict__ pw,
                    const float* __restrict__ vw, float* __restrict__ R){
  int b=blockIdx.x, t=blockIdx.y;
  int s2=threadIdx.x;
  if (s2<32){
    float acc=0.f;
    for (int h=0;h<16;h++)
      acc += pw[h]*vw[h]*P[(((size_t)(b*16+h)*32)+t)*32 + s2];
    R[((size_t)(b*32+t))*32 + s2] = acc;
  }
}

// ---- XP[b,h,t] = sum_s P[b,h,t,s] * X32(token b,s)  (32x17 modes) ----------
__global__ __launch_bounds__(256) void k_XP(const float* __restrict__ P, const float* __restrict__ X64, float* __restrict__ XP){
  int b=blockIdx.x, h=blockIdx.y, t=blockIdx.z;
  __shared__ float Pr[32];
  if (threadIdx.x<32) Pr[threadIdx.x] = P[(((size_t)(b*16+h)*32)+t)*32 + threadIdx.x];
  __syncthreads();
  size_t obase = ((size_t)((b*16+h)*32+t))*544;
  for (int e=threadIdx.x;e<544;e+=256){
    int j=e/17, c=e%17;
    int i2 = (j<16)? j : (j+32);   // X64 storage rows: 0..15 and 48..63 (Xft 112..127)
    float re=0.f, im=0.f;
    for (int s2=0;s2<32;s2++){
      const float* xp = X64 + (((size_t)(b*32+s2))*(64*33) + i2*33 + c)*2;
      float p = Pr[s2];
      re += p*xp[0]; im += p*xp[1];
    }
    XP[(obase+e)*2]=re; XP[(obase+e)*2+1]=im;
  }
}

// ---- final per-token proj spectrum (32x17) with hermitian-c0 projection ----
__global__ __launch_bounds__(256) void k_Sfin(const float* __restrict__ XP,
                       const float* __restrict__ value_w, const float* __restrict__ vsw, const float* __restrict__ vsb,
                       const float* __restrict__ proj_w, const float* __restrict__ psw,
                       float* __restrict__ Sfin){
  int bt=blockIdx.x; int b=bt>>5, t=bt&31;
  __shared__ float XPs[544*2];
  float ar[3]={0,0,0}, ai[3]={0,0,0};
  for (int h=0;h<16;h++){
    __syncthreads();
    const float* src = XP + (((size_t)((b*16+h)*32+t))*544)*2;
    for (int i=threadIdx.x;i<1088;i+=256) XPs[i]=src[i];
    __syncthreads();
    float vw = vsw[h], vb = vsb[h], pw = psw[h];
    for (int u=0;u<3;u++){
      int e = threadIdx.x + u*256;
      if (e>=544) break;
      int j=e/17, c=e%17;
      float xr=XPs[e*2], xi=XPs[e*2+1];
      float wvr=0.f, wvi=0.f;
      if (c<=8 && (j<8 || j>=24)){                 // v-mode support
        int jw = (j<8)? j : (j-16);                // value_w row
        const float* wv = value_w + ((size_t)(h*16+jw)*9 + c)*2;
        wvr=wv[0]; wvi=wv[1];
      }
      float Mr = xr*wvr - xi*wvi;                  // M = XP * Wv
      float Mi = xr*wvi + xi*wvr;
      float Mhr=Mr, Mhi=Mi;
      if (c==0){                                   // hermitian projection at col 0
        float Pr2=0.f, Pi2=0.f;
        int jp2 = (j==0)? 0 : ((j==16)? -1 : 32-j);
        if (jp2>=0 && (jp2<8 || jp2>=24)){
          int jw2 = (jp2<8)? jp2 : (jp2-16);
          const float* wv2 = value_w + ((size_t)(h*16+jw2)*9)*2;
          float pxr=XPs[(jp2*17)*2], pxi=XPs[(jp2*17)*2+1];
          Pr2 = pxr*wv2[0] - pxi*wv2[1];
          Pi2 = pxr*wv2[1] + pxi*wv2[0];
        }
        Mhr = 0.5f*(Mr + Pr2);
        Mhi = 0.5f*(Mi - Pi2);
      }
      float Yr = vw*xr + Mhr + ((e==0)? vb : 0.f); // rfft2(attn[h]) on proj support
      float Yi = vw*xi + Mhi;
      const float* pc = proj_w + ((size_t)(h*32+j)*17 + c)*2;
      float pr=pc[0], pi=pc[1];
      ar[u] += pr*Yr - pi*Yi + pw*Mr;              // + pw*Mv (skip path, folded)
      ai[u] += pr*Yi + pi*Yr + pw*Mi;
    }
  }
  for (int u=0;u<3;u++){
    int e = threadIdx.x + u*256;
    if (e<544){ Sfin[((size_t)bt*544+e)*2]=ar[u]; Sfin[((size_t)bt*544+e)*2+1]=ai[u]; }
  }
}

// ---- skipmix[b,t,:] = sum_s R[b,t,s]*tn[b,s,:] -----------------------------
__global__ __launch_bounds__(256) void k_skipmix(const float* __restrict__ tn, const float* __restrict__ R, float* __restrict__ out){
  int b=blockIdx.x, ch=blockIdx.y;
  int base = ch*512;
  __shared__ float Rs[32][32];
  for (int i=threadIdx.x;i<1024;i+=256) Rs[i>>5][i&31] = R[(size_t)b*1024 + i];
  __syncthreads();
  float a0[32], a1[32];
  #pragma unroll
  for (int t2=0;t2<32;t2++){ a0[t2]=0.f; a1[t2]=0.f; }
  for (int s2=0;s2<32;s2++){
    const float* tp = tn + ((size_t)(b*32+s2))*NPIX + base;
    float v0 = tp[threadIdx.x], v1 = tp[threadIdx.x+256];
    #pragma unroll
    for (int t2=0;t2<32;t2++){ float r=Rs[t2][s2]; a0[t2]+=r*v0; a1[t2]+=r*v1; }
  }
  #pragma unroll
  for (int t2=0;t2<32;t2++){
    float* op = out + ((size_t)(b*32+t2))*NPIX + base;
    op[threadIdx.x]=a0[t2]; op[threadIdx.x+256]=a1[t2];
  }
}

// ============================ NEW TAIL ======================================
// z = irfft(Sfin) + skipmix + x + Cb.  All later norms become per-token affine
// scalars computed analytically from partial sums (slab-parallel, no atomics).

// ---- slab irfft of a 32x17-mode spectrum + optional adds -> field + stats --
// mode 0 (proj): field = irfft(Sfin) + sk + x + Cb, partial (sum,sq) -> pstat[2]
// mode 1 (mixer1): Ss = spec*wm; field = irfft; partial (sum,sq)
// mode 2 (mixer2): Ss = spec*wm; field = irfft; partials over
//                  (f2, f2^2, m1, m1^2, f2*m1) with m1 recomputed from f1,z.
__global__ __launch_bounds__(256) void k_field(const float* __restrict__ Sfin,
        const float* __restrict__ wm,
        const float* __restrict__ sk, const float* __restrict__ x,
        const float* __restrict__ f1, const float* __restrict__ z,
        const float* __restrict__ Sc,
        const float* __restrict__ psw, const float* __restrict__ vsb, const float* __restrict__ psb,
        const float* __restrict__ n2b, const float* __restrict__ mnb1,
        const float* __restrict__ msw1, const float* __restrict__ msb1,
        float* __restrict__ fieldout, float* __restrict__ pstat, int mode){
  int bt = blockIdx.x, slab = blockIdx.y;   // slab = 16 rows (2048 px)
  __shared__ float Ss[1088];
  __shared__ float T[16*17*2];
  __shared__ float tw[128][2];
  if (mode==0){
    for (int i=threadIdx.x;i<1088;i+=256) Ss[i]=Sfin[(size_t)bt*1088+i];
  } else {
    for (int e=threadIdx.x;e<544;e+=256){
      float xr=Sfin[((size_t)bt*544+e)*2], xi=Sfin[((size_t)bt*544+e)*2+1];
      float wr=wm[e*2], wi=wm[e*2+1];
      Ss[e*2]=xr*wr-xi*wi; Ss[e*2+1]=xr*wi+xi*wr;
    }
  }
  for (int p=threadIdx.x;p<128;p+=256){ float sn,cs; sincosf((2.f*PI_F/128.f)*(float)p,&sn,&cs); tw[p][0]=cs; tw[p][1]=sn; }
  __syncthreads();
  int h0 = slab*16;
  for (int e=threadIdx.x;e<16*17;e+=256){
    int hl=e/17, c=e%17; int h=h0+hl;
    float re=0.f, im=0.f;
    for (int j=0;j<32;j++){
      int r=(j<16)? j : (j+96);
      int p=(r*h)&127;
      float cs=tw[p][0], sn=tw[p][1];
      float ar=Ss[(j*17+c)*2], ai=Ss[(j*17+c)*2+1];
      re += ar*cs - ai*sn;
      im += ar*sn + ai*cs;
    }
    T[e*2]=re; T[e*2+1]=im;
  }
  __syncthreads();
  size_t base = (size_t)bt*NPIX + h0*128;
  if (mode==0){
    float Cb = psb[0];
    for (int hh=0;hh<16;hh++) Cb += psw[hh]*vsb[hh];
    float sum=0.f, sq=0.f;
    for (int pos=threadIdx.x;pos<2048;pos+=256){
      int hl=pos>>7, w=pos&127;
      const float* Th=T+hl*17*2;
      float br=tw[w][0], bi=tw[w][1];
      float rr=br, ri=bi;
      float v=Th[0];
      for (int c=1;c<17;c++){
        v += 2.f*(Th[c*2]*rr - Th[c*2+1]*ri);
        float nr=rr*br-ri*bi; ri=rr*bi+ri*br; rr=nr;
      }
      float val = v + sk[base+pos] + x[base+pos] + Cb;
      fieldout[base+pos]=val; sum+=val; sq+=val*val;
    }
    block_reduce2(sum,sq);
    if (threadIdx.x==0){ float* o=pstat+((size_t)bt*8+slab)*2; o[0]=sum; o[1]=sq; }
  } else if (mode==1){
    float sum=0.f, sq=0.f;
    for (int pos=threadIdx.x;pos<2048;pos+=256){
      int hl=pos>>7, w=pos&127;
      const float* Th=T+hl*17*2;
      float br=tw[w][0], bi=tw[w][1];
      float rr=br, ri=bi;
      float v=Th[0];
      for (int c=1;c<17;c++){
        v += 2.f*(Th[c*2]*rr - Th[c*2+1]*ri);
        float nr=rr*br-ri*bi; ri=rr*bi+ri*br; rr=nr;
      }
      fieldout[base+pos]=v; sum+=v; sq+=v*v;
    }
    block_reduce2(sum,sq);
    if (threadIdx.x==0){ float* o=pstat+((size_t)bt*8+slab)*2; o[0]=sum; o[1]=sq; }
  } else {
    const float* Sp = Sc + bt*16;
    float muZ=Sp[0], a0=Sp[2], mu1=Sp[3], c1=Sp[4];
    float b2=n2b[0], nb1=mnb1[0], sw1=msw1[0], sb1=msb1[0];
    float s_f=0.f,s_fsq=0.f,s_m=0.f,s_msq=0.f,s_x=0.f;
    for (int pos=threadIdx.x;pos<2048;pos+=256){
      int hl=pos>>7, w=pos&127;
      const float* Th=T+hl*17*2;
      float br=tw[w][0], bi=tw[w][1];
      float rr=br, ri=bi;
      float v=Th[0];
      for (int c=1;c<17;c++){
        v += 2.f*(Th[c*2]*rr - Th[c*2+1]*ri);
        float nr=rr*br-ri*bi; ri=rr*bi+ri*br; rr=nr;
      }
      size_t gi=base+pos;
      float m0v=(z[gi]-muZ)*a0+b2;
      float y=(f1[gi]-mu1)*c1+nb1 + m0v*sw1 + sb1;
      float m1v=gelu_f(y);
      fieldout[gi]=v;
      s_f+=v; s_fsq+=v*v; s_m+=m1v; s_msq+=m1v*m1v; s_x+=v*m1v;
    }
    block_reduce2(s_f,s_fsq);
    block_reduce2(s_m,s_msq);
    s_x = block_reduce1(s_x);
    if (threadIdx.x==0){
      float* o=pstat+((size_t)bt*8+slab)*5;
      o[0]=s_f; o[1]=s_fsq; o[2]=s_m; o[3]=s_msq; o[4]=s_x;
    }
  }
}

// ---- scalar kernels: per-token norm constants ------------------------------
// Sc layout (stride 16): [0]muZ [1]aA(a2 scale) [2]a0(m0 scale)
//                        [3]mu1 [4]c1  [5]mu2f [6]c2  [7]mu3 [8]c3
__global__ void k_scalA(const float* __restrict__ pstat, const float* __restrict__ ag,
                        const float* __restrict__ n2g, float* __restrict__ Sc){
  int t=threadIdx.x;
  float sum=0.f,sq=0.f;
  for (int s=0;s<8;s++){ const float* p=pstat+((size_t)t*8+s)*2; sum+=p[0]; sq+=p[1]; }
  const float iN=1.f/NPIX;
  float mu=sum*iN, var=sq*iN-mu*mu;
  float inv=rsqrtf(var+1e-5f);
  float aA=inv*ag[0];
  float var2=aA*aA*var;
  float a0=aA*rsqrtf(var2+1e-5f)*n2g[0];
  float* o=Sc+t*16; o[0]=mu; o[1]=aA; o[2]=a0;
}

__global__ void k_scalB(const float* __restrict__ pstat, const float* __restrict__ mng1,
                        float* __restrict__ Sc){
  int t=threadIdx.x;
  float sum=0.f,sq=0.f;
  for (int s=0;s<8;s++){ const float* p=pstat+((size_t)t*8+s)*2; sum+=p[0]; sq+=p[1]; }
  const float iN=1.f/NPIX;
  float mu=sum*iN, var=sq*iN-mu*mu;
  float c1=rsqrtf(var+1e-5f)*mng1[0];
  float* o=Sc+t*16; o[3]=mu; o[4]=c1;
}

__global__ void k_scalC(const float* __restrict__ pstat, const float* __restrict__ mng2,
                        const float* __restrict__ mnb2, const float* __restrict__ msw2,
                        const float* __restrict__ msb2, const float* __restrict__ outg,
                        float* __restrict__ Sc){
  int t=threadIdx.x;
  float sf=0.f,sfsq=0.f,sm=0.f,smsq=0.f,sx=0.f;
  for (int s=0;s<8;s++){
    const float* p=pstat+((size_t)t*8+s)*5;
    sf+=p[0]; sfsq+=p[1]; sm+=p[2]; smsq+=p[3]; sx+=p[4];
  }
  const float iN=1.f/NPIX;
  float mu2f=sf*iN, var2=sfsq*iN-mu2f*mu2f;
  float c2=rsqrtf(var2+1e-5f)*mng2[0];
  float Em1=sm*iN, Em1sq=smsq*iN, Exm=sx*iN;
  float sw=msw2[0], K=mnb2[0]+msb2[0];
  float Em2=K+sw*Em1;
  float Em2sq = c2*c2*var2 + sw*sw*Em1sq + K*K
              + 2.f*c2*sw*(Exm - mu2f*Em1) + 2.f*K*sw*Em1;
  float var_m2=Em2sq-Em2*Em2;
  float c3=rsqrtf(var_m2+1e-5f)*outg[0];
  float* o=Sc+t*16; o[5]=mu2f; o[6]=c2; o[7]=Em2; o[8]=c3;
}

// ---- column DFT of m0 (mode 0) or m1 (mode 1), computed on the fly ---------
__global__ __launch_bounds__(256) void k_colA(const float* __restrict__ f1, const float* __restrict__ z,
        const float* __restrict__ Sc, const float* __restrict__ n2b,
        const float* __restrict__ mnb1, const float* __restrict__ msw1, const float* __restrict__ msb1,
        float* __restrict__ A, int mode){
  __shared__ float rows[32*128];
  int grow = blockIdx.x*32;            // global row = token*128 + h
  int t = grow>>7;
  const float* Sp = Sc + t*16;
  float muZ=Sp[0], a0=Sp[2];
  float b2 = n2b[0];
  if (mode==0){
    for (int i=threadIdx.x;i<4096;i+=256){
      float zv = z[(size_t)grow*128 + i];
      rows[i] = (zv-muZ)*a0 + b2;
    }
  } else {
    float mu1=Sp[3], c1=Sp[4];
    float nb=mnb1[0], sw=msw1[0], sb=msb1[0];
    for (int i=threadIdx.x;i<4096;i+=256){
      size_t gi=(size_t)grow*128+i;
      float m0v=(z[gi]-muZ)*a0+b2;
      float y=(f1[gi]-mu1)*c1+nb + m0v*sw + sb;
      rows[i]=gelu_f(y);
    }
  }
  __syncthreads();
  for (int e=threadIdx.x;e<544;e+=256){
    int r=e/17, c=e%17;
    const float* rp=rows+r*128;
    float sn,cs; sincosf(-(2.f*PI_F/128.f)*(float)c,&sn,&cs);
    float rr=1.f, ri=0.f, re=0.f, im=0.f;
    for (int w=0;w<128;w++){
      float v=rp[w];
      re+=v*rr; im+=v*ri;
      float nr=rr*cs-ri*sn; ri=rr*sn+ri*cs; rr=nr;
    }
    float* o=A+((size_t)(grow+r)*17+c)*2;
    o[0]=re; o[1]=im;
  }
}

// ---- forward 32x17 modes (rows 0..15, 112..127) for mixer ------------------
__global__ __launch_bounds__(256) void k_rowfft32(const float* __restrict__ A, float* __restrict__ spec){
  int s=blockIdx.x;
  __shared__ float a[128*17*2];
  __shared__ float tw[128][2];
  for (int i=threadIdx.x;i<128*17*2;i+=256) a[i]=A[(size_t)s*(128*17*2)+i];
  for (int p=threadIdx.x;p<128;p+=256){ float sn,cs; sincosf(-(2.f*PI_F/128.f)*(float)p,&sn,&cs); tw[p][0]=cs; tw[p][1]=sn; }
  __syncthreads();
  const float sc=1.f/16384.f;
  for (int e=threadIdx.x;e<544;e+=256){
    int j=e/17, c=e%17;
    int r=(j<16)? j : (j+96);
    float re=0.f,im=0.f;
    for (int h=0;h<128;h++){
      int p=(r*h)&127;
      float cs=tw[p][0], sn=tw[p][1];
      float ar=a[(h*17+c)*2], ai=a[(h*17+c)*2+1];
      re += ar*cs - ai*sn;
      im += ar*sn + ai*cs;
    }
    spec[((size_t)s*544+e)*2]=re*sc; spec[((size_t)s*544+e)*2+1]=im*sc;
  }
}

// ---- final: out = norm(m2)+a2, everything recomputed from z,f1,f2 ----------
__global__ __launch_bounds__(256) void k_final2(const float* __restrict__ z, const float* __restrict__ f1,
        const float* __restrict__ f2, const float* __restrict__ Sc,
        const float* __restrict__ ab, const float* __restrict__ n2b,
        const float* __restrict__ mnb1, const float* __restrict__ msw1, const float* __restrict__ msb1,
        const float* __restrict__ mnb2, const float* __restrict__ msw2, const float* __restrict__ msb2,
        const float* __restrict__ outb, float* __restrict__ out){
  int bt=blockIdx.x, slab=blockIdx.y;
  const float* Sp=Sc+bt*16;
  float muZ=Sp[0],aA=Sp[1],a0=Sp[2],mu1=Sp[3],c1=Sp[4],mu2f=Sp[5],c2=Sp[6],mu3=Sp[7],c3=Sp[8];
  float b1=ab[0], b2=n2b[0], nb1=mnb1[0], sw1=msw1[0], sb1=msb1[0];
  float nb2=mnb2[0], sw2=msw2[0], sb2=msb2[0], bo=outb[0];
  size_t base=(size_t)bt*NPIX + (size_t)slab*2048;
  for (int i=threadIdx.x;i<2048;i+=256){
    size_t gi=base+i;
    float zv=z[gi];
    float m0v=(zv-muZ)*a0+b2;
    float a2v=(zv-muZ)*aA+b1;
    float y=(f1[gi]-mu1)*c1+nb1 + m0v*sw1 + sb1;
    float m1v=gelu_f(y);
    float m2v=(f2[gi]-mu2f)*c2+nb2 + m1v*sw2 + sb2;
    out[gi]=(m2v-mu3)*c3+bo+a2v;
  }
}

extern "C" void kernel_launch(void* const* d_in, const int* in_sizes, int n_in,
                              void* d_out, int out_size, void* d_ws, size_t ws_size,
                              hipStream_t stream){
  const float* x        = (const float*)d_in[0];
  const float* key_w    = (const float*)d_in[1];
  const float* key_sw   = (const float*)d_in[2];
  const float* key_sb   = (const float*)d_in[3];
  const float* query_w  = (const float*)d_in[4];
  const float* query_sw = (const float*)d_in[5];
  const float* query_sb = (const float*)d_in[6];
  const float* value_w  = (const float*)d_in[7];
  const float* value_sw = (const float*)d_in[8];
  const float* value_sb = (const float*)d_in[9];
  const float* proj_w   = (const float*)d_in[10];
  const float* proj_sw  = (const float*)d_in[11];
  const float* proj_sb  = (const float*)d_in[12];
  const float* norm1_g  = (const float*)d_in[13];
  const float* norm1_b  = (const float*)d_in[14];
  const float* attn_g   = (const float*)d_in[15];
  const float* attn_b   = (const float*)d_in[16];
  const float* norm2_g  = (const float*)d_in[17];
  const float* norm2_b  = (const float*)d_in[18];
  const float* mw1      = (const float*)d_in[19];
  const float* msw1     = (const float*)d_in[20];
  const float* msb1     = (const float*)d_in[21];
  const float* mng1     = (const float*)d_in[22];
  const float* mnb1     = (const float*)d_in[23];
  const float* mw2      = (const float*)d_in[24];
  const float* msw2     = (const float*)d_in[25];
  const float* msb2     = (const float*)d_in[26];
  const float* mng2     = (const float*)d_in[27];
  const float* mnb2     = (const float*)d_in[28];
  const float* outg     = (const float*)d_in[29];
  const float* outb     = (const float*)d_in[30];
  float* out = (float*)d_out;
  float* ws  = (float*)d_ws;

  size_t off=0;
  float* tn  = ws + off; off += (size_t)128*16384;     // tokens_norm
  float* A   = ws + off; off += (size_t)128*128*33*2;  // column-DFT temp (max size)
  float* X64 = ws + off; off += (size_t)128*64*33*2;   // 64x33 spectrum of tn (raw)
  float* X64h= ws + off; off += (size_t)128*64*33*2;   // hermitianized (cols 0,32)
  float* Zq  = ws + off; off += (size_t)128*16*306;    // per (t,h) q spectra
  float* Zk  = ws + off; off += (size_t)128*16*306;    // per (t,h) k spectra (w-folded)
  float* Ue  = ws + off; off += (size_t)4*32*32;       // head-indep complementary gram
  float* P   = ws + off; off += (size_t)4*16*32*32;    // softmaxed attention
  float* R   = ws + off; off += (size_t)4*32*32;       // token-mix matrix
  float* XPb = ws + off; off += (size_t)2048*544*2;    // mixed 32x17 spectra per (b,h,t)
  float* Sf  = ws + off; off += (size_t)128*544*2;     // final proj spectrum per token
  float* sk  = ws + off; off += (size_t)128*16384;     // skipmix
  float* zf  = ws + off; off += (size_t)128*16384;     // z field (pre-norm attn)
  float* fd1 = ws + off; off += (size_t)128*16384;     // mixer1 spectral field
  float* fd2 = ws + off; off += (size_t)128*16384;     // mixer2 spectral field
  float* sp  = ws + off; off += (size_t)128*544*2;     // mixer spectrum
  float* pstatA = ws + off; off += (size_t)128*8*2;
  float* pstatB = ws + off; off += (size_t)128*8*2;
  float* pstatC = ws + off; off += (size_t)128*8*5;
  float* Sc  = ws + off; off += (size_t)128*16;        // per-token norm scalars

  k_norm_x<<<128,256,0,stream>>>(x, norm1_g, norm1_b, tn);
  k_colfft<33><<<512,256,0,stream>>>(tn, A);
  k_rowfft64<<<128,256,0,stream>>>(A, X64, X64h);
  k_Z<<<128,256,0,stream>>>(X64, X64h, query_w, query_sw, key_w, key_sw, Zq, Zk);
  k_Ue<<<dim3(4,32),256,0,stream>>>(X64h, Ue);
  k_scores2<<<dim3(4,16),256,0,stream>>>(Zq, Zk, Ue, query_sw, query_sb, key_sw, key_sb, P);
  k_R<<<dim3(4,32),64,0,stream>>>(P,proj_sw,value_sw,R);
  k_XP<<<dim3(4,16,32),256,0,stream>>>(P,X64,XPb);
  k_Sfin<<<128,256,0,stream>>>(XPb,value_w,value_sw,value_sb,proj_w,proj_sw,Sf);
  k_skipmix<<<dim3(4,32),256,0,stream>>>(tn,R,sk);

  // proj field: z = irfft(Sf)+sk+x+Cb
  k_field<<<dim3(128,8),256,0,stream>>>(Sf, nullptr, sk, x, nullptr, nullptr, nullptr,
      proj_sw, value_sb, proj_sb, nullptr, nullptr, nullptr, nullptr, zf, pstatA, 0);
  k_scalA<<<1,128,0,stream>>>(pstatA, attn_g, norm2_g, Sc);
  // fft2(m0) with m0 recomputed affine from z
  k_colA<<<512,256,0,stream>>>(zf, zf, Sc, norm2_b, mnb1, msw1, msb1, A, 0);
  k_rowfft32<<<128,256,0,stream>>>(A, sp);
  // mixer1 spectral field
  k_field<<<dim3(128,8),256,0,stream>>>(sp, mw1, nullptr, nullptr, nullptr, nullptr, nullptr,
      nullptr, nullptr, nullptr, nullptr, nullptr, nullptr, nullptr, fd1, pstatB, 1);
  k_scalB<<<1,128,0,stream>>>(pstatB, mng1, Sc);
  // fft2(m1) with m1 = gelu(norm(fd1)+m0*sw+sb) recomputed on the fly
  k_colA<<<512,256,0,stream>>>(fd1, zf, Sc, norm2_b, mnb1, msw1, msb1, A, 1);
  k_rowfft32<<<128,256,0,stream>>>(A, sp);
  // mixer2 spectral field + cross-moment stats of m2
  k_field<<<dim3(128,8),256,0,stream>>>(sp, mw2, nullptr, nullptr, fd1, zf, Sc,
      nullptr, nullptr, nullptr, norm2_b, mnb1, msw1, msb1, fd2, pstatC, 2);
  k_scalC<<<1,128,0,stream>>>(pstatC, mng2, mnb2, msw2, msb2, outg, Sc);
  k_final2<<<dim3(128,8),256,0,stream>>>(zf, fd1, fd2, Sc, attn_b, norm2_b,
      mnb1, msw1, msb1, mnb2, msw2, msb2, outb, out);
}

// Round 4
// 374.683 us; speedup vs baseline: 2.1589x; 1.3468x over previous
//
#include <hip/hip_runtime.h>
#include <cmath>

#define PI_F 3.14159265358979323846f
#define NTOK 128
#define NPIX 16384
#define NHEADS 16

__device__ __forceinline__ void block_reduce2(float& a, float& b){
  __shared__ float sa[4], sb[4];
  __syncthreads();
  for (int o=32;o>0;o>>=1){ a += __shfl_down(a,o); b += __shfl_down(b,o); }
  int w = threadIdx.x>>6, l = threadIdx.x&63;
  if (l==0){ sa[w]=a; sb[w]=b; }
  __syncthreads();
  a = sa[0]+sa[1]+sa[2]+sa[3];
  b = sb[0]+sb[1]+sb[2]+sb[3];
}

__device__ __forceinline__ float block_reduce1(float a){
  __shared__ float sa[4];
  __syncthreads();
  for (int o=32;o>0;o>>=1) a += __shfl_down(a,o);
  int w = threadIdx.x>>6, l = threadIdx.x&63;
  if (l==0) sa[w]=a;
  __syncthreads();
  return sa[0]+sa[1]+sa[2]+sa[3];
}

__device__ __forceinline__ float gelu_f(float y){
  return 0.5f*y*(1.f + erff(y*0.70710678118f));
}

// ---- slab stats of x (for norm1 affine) ------------------------------------
__global__ __launch_bounds__(256) void k_stats0(const float* __restrict__ x, float* __restrict__ pstat){
  int t=blockIdx.x, slab=blockIdx.y;
  const float* xs = x + (size_t)t*NPIX + slab*2048;
  float sum=0.f, sq=0.f;
  for (int i=threadIdx.x;i<2048;i+=256){ float v=xs[i]; sum+=v; sq+=v*v; }
  block_reduce2(sum,sq);
  if (threadIdx.x==0){ float* o=pstat+((size_t)t*8+slab)*2; o[0]=sum; o[1]=sq; }
}

__global__ void k_scal0(const float* __restrict__ pstat, const float* __restrict__ g,
                        const float* __restrict__ b, float* __restrict__ Sc0){
  int t=threadIdx.x;
  float sum=0.f,sq=0.f;
  for (int s=0;s<8;s++){ const float* p=pstat+((size_t)t*8+s)*2; sum+=p[0]; sq+=p[1]; }
  const float iN=1.f/NPIX;
  float mu=sum*iN, var=sq*iN-mu*mu;
  float a=rsqrtf(var+1e-5f)*g[0];
  Sc0[t*2]=a; Sc0[t*2+1]=b[0]-mu*a;   // tn = a*x + b0
}

// ---- Column DFT of tn (affine-folded), 16 rows per block -------------------
__global__ __launch_bounds__(256) void k_colfft33(const float* __restrict__ x, const float* __restrict__ Sc0,
                          float* __restrict__ A){
  __shared__ float rows[16*128];
  __shared__ float tw[128][2];
  int base = blockIdx.x*16;          // global row index (token*128 + h)
  int t = base>>7;
  float a=Sc0[t*2], b0=Sc0[t*2+1];
  for (int i=threadIdx.x;i<2048;i+=256) rows[i] = a*x[(size_t)base*128 + i] + b0;
  for (int p=threadIdx.x;p<128;p+=256){ float sn,cs; sincosf(-(2.f*PI_F/128.f)*(float)p,&sn,&cs); tw[p][0]=cs; tw[p][1]=sn; }
  __syncthreads();
  for (int e=threadIdx.x;e<16*33;e+=256){
    int r=e/33, c=e%33;
    const float* rp=rows+r*128;
    float re=0.f, im=0.f;
    for (int w=0;w<128;w++){
      int p=(c*w)&127;
      float v=rp[w];
      re+=v*tw[p][0]; im+=v*tw[p][1];
    }
    float* o=A+((size_t)(base+r)*33+c)*2; o[0]=re; o[1]=im;
  }
}

// ---- Row DFT -> 64x33 spectrum, column-group parallel ----------------------
__global__ __launch_bounds__(256) void k_rowfft64(const float* __restrict__ A,
                          float* __restrict__ X64, float* __restrict__ X64h){
  int s=blockIdx.x, cg=blockIdx.y;   // 3 groups of 11 cols
  int c0=cg*11;
  __shared__ float a[128][11][2];
  __shared__ float S[64][11][2];
  __shared__ float tw[128][2];
  for (int i=threadIdx.x;i<128*22;i+=256){
    int r=i/22, q=i%22;
    a[r][q>>1][q&1] = A[((size_t)(s*128+r)*33 + c0)*2 + q];
  }
  for (int p=threadIdx.x;p<128;p+=256){ float sn,cs; sincosf(-(2.f*PI_F/128.f)*(float)p,&sn,&cs); tw[p][0]=cs; tw[p][1]=sn; }
  __syncthreads();
  const float sc=1.f/16384.f;
  for (int e=threadIdx.x;e<64*11;e+=256){
    int i2=e/11, cl=e%11;
    int r=(i2<32)? i2 : i2+64;
    float re=0.f, im=0.f;
    for (int h=0;h<128;h++){
      int p=(r*h)&127;
      float cs=tw[p][0], sn=tw[p][1];
      float ar=a[h][cl][0], ai=a[h][cl][1];
      re+=ar*cs-ai*sn; im+=ar*sn+ai*cs;
    }
    S[i2][cl][0]=re*sc; S[i2][cl][1]=im*sc;
  }
  __syncthreads();
  for (int e=threadIdx.x;e<64*11;e+=256){
    int r=e/11, cl=e%11; int c=c0+cl;
    float vr=S[r][cl][0], vi=S[r][cl][1];
    float* o=X64+((size_t)s*(64*33)+r*33+c)*2; o[0]=vr; o[1]=vi;
    float hr=vr, hi=vi;
    if (c==0 || c==32){
      int pr=(64-r)&63;
      hr=0.5f*(vr+S[pr][cl][0]);
      hi=0.5f*(vi-S[pr][cl][1]);
    }
    float* oh=X64h+((size_t)s*(64*33)+r*33+c)*2; oh[0]=hr; oh[1]=hi;
  }
}

// ---- Z vectors: per (token,head) 17x9-mode effective q/k spectra -----------
__global__ __launch_bounds__(256) void k_Z(const float* __restrict__ X64, const float* __restrict__ X64h,
                    const float* __restrict__ qw, const float* __restrict__ qsw,
                    const float* __restrict__ kw, const float* __restrict__ ksw,
                    float* __restrict__ Zq, float* __restrict__ Zk){
  int t = blockIdx.x;
  __shared__ float2 xr[153], xh[153];
  for (int i=threadIdx.x;i<306;i+=256){
    int side=i/153, m=i%153;
    int j=m/9, c=m%9;
    int r = (j<=8)? j : j+47;
    const float* src = (side? X64h : X64) + ((size_t)t*(64*33) + r*33 + c)*2;
    float2 v; v.x=src[0]; v.y=src[1];
    if (side) xh[m]=v; else xr[m]=v;
  }
  __syncthreads();
  for (int h=0;h<16;h++){
    float aq=qsw[h], ak=ksw[h];
    for (int e=threadIdx.x;e<306;e+=256){
      int side=e/153, m=e%153;
      int j=m/9, c=m%9;
      const float* W = side? kw : qw;
      float a = side? ak : aq;
      float2 pr; pr.x=0.f; pr.y=0.f;
      if (j!=8){
        int jw=(j<8)? j : j-1;
        const float* wp = W + ((size_t)(h*16+jw)*9 + c)*2;
        float2 x = xr[m];
        pr.x = wp[0]*x.x - wp[1]*x.y;
        pr.y = wp[0]*x.y + wp[1]*x.x;
      }
      float2 V = pr;
      if (c==0){
        int jp = (j==0)? 0 : 17-j;
        float2 pp; pp.x=0.f; pp.y=0.f;
        if (jp!=8){
          int jw2=(jp<8)? jp : jp-1;
          const float* wp2 = W + ((size_t)(h*16+jw2)*9 + 0)*2;
          float2 x2 = xr[jp*9];
          pp.x = wp2[0]*x2.x - wp2[1]*x2.y;
          pp.y = wp2[0]*x2.y + wp2[1]*x2.x;
        }
        V.x = 0.5f*(pr.x + pp.x);
        V.y = 0.5f*(pr.y - pp.y);
      }
      float2 xm = xh[m];
      float zr = a*xm.x + V.x;
      float zi = a*xm.y + V.y;
      float wf = (side && c!=0)? 2.f : 1.f;
      float* dst = (side? Zk : Zq) + ((size_t)(t*16+h))*306 + m*2;
      dst[0]=wf*zr; dst[1]=wf*zi;
    }
  }
}

// ---- Ue[b,t,s]: head-independent gram, 4 s-values per block ----------------
__global__ __launch_bounds__(256) void k_Ue(const float* __restrict__ X64h, float* __restrict__ Ue){
  int b=blockIdx.x, t=blockIdx.y, sg=blockIdx.z;
  __shared__ float2 xt[2112];
  const float2* src = (const float2*)(X64h + ((size_t)(b*32+t))*4224);
  for (int m=threadIdx.x;m<2112;m+=256){
    int r=m/33, c=m%33;
    bool excl = (c<=8) && (r<=8 || r>=56);
    float w = excl? 0.f : ((c==0||c==32)? 1.f : 2.f);
    float2 v = src[m];
    xt[m]=make_float2(v.x*w, v.y*w);
  }
  __syncthreads();
  float acc[4]={0.f,0.f,0.f,0.f};
  const float2* s0=(const float2*)(X64h + ((size_t)(b*32+sg*4))*4224);
  for (int m=threadIdx.x;m<2112;m+=256){
    float2 a2=xt[m];
    #pragma unroll
    for (int j=0;j<4;j++){
      float2 b2=s0[(size_t)j*2112+m];
      acc[j]+=a2.x*b2.x+a2.y*b2.y;
    }
  }
  for (int j=0;j<4;j++){
    float r=block_reduce1(acc[j]);
    if (threadIdx.x==0) Ue[((size_t)(b*32+t))*32 + sg*4+j]=r;
  }
}

// ---- raw scores (pre-softmax), s-half parallel -----------------------------
__global__ __launch_bounds__(256) void k_scores_raw(const float* __restrict__ Zq, const float* __restrict__ Zk,
                          const float* __restrict__ Ue,
                          const float* __restrict__ qsw, const float* __restrict__ qsb,
                          const float* __restrict__ ksw, const float* __restrict__ ksb,
                          float* __restrict__ P){
  int b=blockIdx.x, h=blockIdx.y, ch=blockIdx.z;
  __shared__ float2 zq[32][154];
  __shared__ float2 zk[16][154];
  for (int i=threadIdx.x;i<32*153;i+=256){
    int t=i/153, m=i%153;
    zq[t][m]=((const float2*)(Zq + ((size_t)((b*32+t)*16+h))*306))[m];
  }
  for (int i=threadIdx.x;i<16*153;i+=256){
    int s=i/153, m=i%153;
    zk[s][m]=((const float2*)(Zk + ((size_t)((b*32+ch*16+s)*16+h))*306))[m];
  }
  __syncthreads();
  float aqak=qsw[h]*ksw[h], bq=qsb[h], bk=ksb[h];
  int t=threadIdx.x>>3, sl=threadIdx.x&7;
  for (int u=0;u<2;u++){
    int sr=sl+u*8; int s=ch*16+sr;
    float acc=0.f;
    for (int m=0;m<153;m++){
      float2 a2=zq[t][m], c2=zk[sr][m];
      acc+=a2.x*c2.x+a2.y*c2.y;
    }
    float G=aqak*Ue[((size_t)(b*32+t))*32+s]+acc;
    P[((size_t)(b*16+h)*32+t)*32+s]=64.f*(G + bk*zq[t][0].x + bq*zk[sr][0].x + bq*bk);
  }
}

// ---- softmax: one 32-lane group per row ------------------------------------
__global__ __launch_bounds__(256) void k_softmax2(float* __restrict__ P){
  int row=blockIdx.x*8+(threadIdx.x>>5), lane=threadIdx.x&31;
  float* p=P+(size_t)row*32;
  float v=p[lane];
  float m=v;
  for (int o=16;o>0;o>>=1) m=fmaxf(m,__shfl_xor(m,o,32));
  float e=expf(v-m), sum=e;
  for (int o=16;o>0;o>>=1) sum+=__shfl_xor(sum,o,32);
  p[lane]=e/sum;
}

// ---- R (pre-scaled by tn affine): Ra = R*a_s, cb = sum R*b0_s --------------
__global__ __launch_bounds__(64) void k_R(const float* __restrict__ P, const float* __restrict__ pw,
                    const float* __restrict__ vw, const float* __restrict__ Sc0,
                    float* __restrict__ Ra, float* __restrict__ cbv){
  int b=blockIdx.x, t=blockIdx.y;
  int s2=threadIdx.x;
  if (s2<32){
    float acc=0.f;
    for (int h=0;h<16;h++)
      acc += pw[h]*vw[h]*P[(((size_t)(b*16+h)*32)+t)*32 + s2];
    int st=b*32+s2;
    float a=Sc0[st*2], b0=Sc0[st*2+1];
    Ra[((size_t)(b*32+t))*32 + s2] = acc*a;
    float cb=acc*b0;
    for (int o=16;o>0;o>>=1) cb+=__shfl_down(cb,o,32);
    if (s2==0) cbv[b*32+t]=cb;
  }
}

// ---- XP[b,h,t] = sum_s P[b,h,t,s] * X32(token b,s) -------------------------
__global__ __launch_bounds__(256) void k_XP(const float* __restrict__ P, const float* __restrict__ X64, float* __restrict__ XP){
  int b=blockIdx.x, h=blockIdx.y, t=blockIdx.z;
  __shared__ float Pr[32];
  if (threadIdx.x<32) Pr[threadIdx.x] = P[(((size_t)(b*16+h)*32)+t)*32 + threadIdx.x];
  __syncthreads();
  size_t obase = ((size_t)((b*16+h)*32+t))*544;
  for (int e=threadIdx.x;e<544;e+=256){
    int j=e/17, c=e%17;
    int i2 = (j<16)? j : (j+32);
    float re=0.f, im=0.f;
    for (int s2=0;s2<32;s2++){
      const float* xp = X64 + (((size_t)(b*32+s2))*(64*33) + i2*33 + c)*2;
      float p = Pr[s2];
      re += p*xp[0]; im += p*xp[1];
    }
    XP[(obase+e)*2]=re; XP[(obase+e)*2+1]=im;
  }
}

// ---- per-(token,head) proj-spectrum partial --------------------------------
__global__ __launch_bounds__(256) void k_Sfin(const float* __restrict__ XP,
                       const float* __restrict__ value_w, const float* __restrict__ vsw, const float* __restrict__ vsb,
                       const float* __restrict__ proj_w, const float* __restrict__ psw,
                       float* __restrict__ Sfp){
  int bt=blockIdx.x, h=blockIdx.y; int b=bt>>5, t=bt&31;
  __shared__ float XPs[1088];
  const float* src = XP + (((size_t)((b*16+h)*32+t))*544)*2;
  for (int i=threadIdx.x;i<1088;i+=256) XPs[i]=src[i];
  __syncthreads();
  float vw = vsw[h], vb = vsb[h], pw = psw[h];
  for (int u=0;u<3;u++){
    int e = threadIdx.x + u*256;
    if (e>=544) break;
    int j=e/17, c=e%17;
    float xr=XPs[e*2], xi=XPs[e*2+1];
    float wvr=0.f, wvi=0.f;
    if (c<=8 && (j<8 || j>=24)){
      int jw = (j<8)? j : (j-16);
      const float* wv = value_w + ((size_t)(h*16+jw)*9 + c)*2;
      wvr=wv[0]; wvi=wv[1];
    }
    float Mr = xr*wvr - xi*wvi;
    float Mi = xr*wvi + xi*wvr;
    float Mhr=Mr, Mhi=Mi;
    if (c==0){
      float Pr2=0.f, Pi2=0.f;
      int jp2 = (j==0)? 0 : ((j==16)? -1 : 32-j);
      if (jp2>=0 && (jp2<8 || jp2>=24)){
        int jw2 = (jp2<8)? jp2 : (jp2-16);
        const float* wv2 = value_w + ((size_t)(h*16+jw2)*9)*2;
        float pxr=XPs[(jp2*17)*2], pxi=XPs[(jp2*17)*2+1];
        Pr2 = pxr*wv2[0] - pxi*wv2[1];
        Pi2 = pxr*wv2[1] + pxi*wv2[0];
      }
      Mhr = 0.5f*(Mr + Pr2);
      Mhi = 0.5f*(Mi - Pi2);
    }
    float Yr = vw*xr + Mhr + ((e==0)? vb : 0.f);
    float Yi = vw*xi + Mhi;
    const float* pc = proj_w + ((size_t)(h*32+j)*17 + c)*2;
    float pr=pc[0], pi=pc[1];
    float* o = Sfp + ((size_t)(bt*16+h))*1088 + e*2;
    o[0] = pr*Yr - pi*Yi + pw*Mr;
    o[1] = pr*Yi + pi*Yr + pw*Mi;
  }
}

// ---- reduce the 16 per-head partials ---------------------------------------
__global__ __launch_bounds__(256) void k_Sred(const float* __restrict__ Sfp, float* __restrict__ Sf){
  int bt=blockIdx.x; int i0=blockIdx.y*272;
  for (int i=threadIdx.x;i<272;i+=256){
    int e=i0+i;
    float acc=0.f;
    for (int h=0;h<16;h++) acc += Sfp[((size_t)(bt*16+h))*1088 + e];
    Sf[(size_t)bt*1088+e]=acc;
  }
}

// ---- skipmix: out = sum_s Ra[t,s]*x[s,:] + cb[t], 8-token tiles ------------
__global__ __launch_bounds__(256) void k_skipmix(const float* __restrict__ x, const float* __restrict__ Ra,
                          const float* __restrict__ cbv, float* __restrict__ out){
  int b=blockIdx.x, ch=blockIdx.y, tt=blockIdx.z;
  int pxb=ch*512;
  __shared__ float Rs[8][32];
  {
    int i=threadIdx.x;
    if (i<256) Rs[i>>5][i&31] = Ra[((size_t)(b*32+tt*8+(i>>5)))*32 + (i&31)];
  }
  __syncthreads();
  float a0[8], a1[8];
  #pragma unroll
  for (int t=0;t<8;t++){ a0[t]=0.f; a1[t]=0.f; }
  for (int s=0;s<32;s++){
    const float* xp = x + ((size_t)(b*32+s))*NPIX + pxb;
    float v0=xp[threadIdx.x], v1=xp[threadIdx.x+256];
    #pragma unroll
    for (int t=0;t<8;t++){ float r=Rs[t][s]; a0[t]+=r*v0; a1[t]+=r*v1; }
  }
  #pragma unroll
  for (int t=0;t<8;t++){
    int gt=tt*8+t;
    float cb=cbv[b*32+gt];
    float* op = out + ((size_t)(b*32+gt))*NPIX + pxb;
    op[threadIdx.x]=a0[t]+cb; op[threadIdx.x+256]=a1[t]+cb;
  }
}

// ---- slab irfft of a 32x17-mode spectrum + stats ---------------------------
__global__ __launch_bounds__(256) void k_field(const float* __restrict__ Sfin,
        const float* __restrict__ wm,
        const float* __restrict__ sk, const float* __restrict__ x,
        const float* __restrict__ f1, const float* __restrict__ z,
        const float* __restrict__ Sc,
        const float* __restrict__ psw, const float* __restrict__ vsb, const float* __restrict__ psb,
        const float* __restrict__ n2b, const float* __restrict__ mnb1,
        const float* __restrict__ msw1, const float* __restrict__ msb1,
        float* __restrict__ fieldout, float* __restrict__ pstat, int mode){
  int bt = blockIdx.x, slab = blockIdx.y;
  __shared__ float Ss[1088];
  __shared__ float T[16*17*2];
  __shared__ float tw[128][2];
  if (mode==0){
    for (int i=threadIdx.x;i<1088;i+=256) Ss[i]=Sfin[(size_t)bt*1088+i];
  } else {
    for (int e=threadIdx.x;e<544;e+=256){
      float xr=Sfin[((size_t)bt*544+e)*2], xi=Sfin[((size_t)bt*544+e)*2+1];
      float wr=wm[e*2], wi=wm[e*2+1];
      Ss[e*2]=xr*wr-xi*wi; Ss[e*2+1]=xr*wi+xi*wr;
    }
  }
  for (int p=threadIdx.x;p<128;p+=256){ float sn,cs; sincosf((2.f*PI_F/128.f)*(float)p,&sn,&cs); tw[p][0]=cs; tw[p][1]=sn; }
  __syncthreads();
  int h0 = slab*16;
  for (int e=threadIdx.x;e<16*17;e+=256){
    int hl=e/17, c=e%17; int h=h0+hl;
    float re=0.f, im=0.f;
    for (int j=0;j<32;j++){
      int r=(j<16)? j : (j+96);
      int p=(r*h)&127;
      float cs=tw[p][0], sn=tw[p][1];
      float ar=Ss[(j*17+c)*2], ai=Ss[(j*17+c)*2+1];
      re += ar*cs - ai*sn;
      im += ar*sn + ai*cs;
    }
    T[e*2]=re; T[e*2+1]=im;
  }
  __syncthreads();
  size_t base = (size_t)bt*NPIX + h0*128;
  if (mode==0){
    float Cb = psb[0];
    for (int hh=0;hh<16;hh++) Cb += psw[hh]*vsb[hh];
    float sum=0.f, sq=0.f;
    for (int pos=threadIdx.x;pos<2048;pos+=256){
      int hl=pos>>7, w=pos&127;
      const float* Th=T+hl*17*2;
      float br=tw[w][0], bi=tw[w][1];
      float rr=br, ri=bi;
      float v=Th[0];
      for (int c=1;c<17;c++){
        v += 2.f*(Th[c*2]*rr - Th[c*2+1]*ri);
        float nr=rr*br-ri*bi; ri=rr*bi+ri*br; rr=nr;
      }
      float val = v + sk[base+pos] + x[base+pos] + Cb;
      fieldout[base+pos]=val; sum+=val; sq+=val*val;
    }
    block_reduce2(sum,sq);
    if (threadIdx.x==0){ float* o=pstat+((size_t)bt*8+slab)*2; o[0]=sum; o[1]=sq; }
  } else if (mode==1){
    float sum=0.f, sq=0.f;
    for (int pos=threadIdx.x;pos<2048;pos+=256){
      int hl=pos>>7, w=pos&127;
      const float* Th=T+hl*17*2;
      float br=tw[w][0], bi=tw[w][1];
      float rr=br, ri=bi;
      float v=Th[0];
      for (int c=1;c<17;c++){
        v += 2.f*(Th[c*2]*rr - Th[c*2+1]*ri);
        float nr=rr*br-ri*bi; ri=rr*bi+ri*br; rr=nr;
      }
      fieldout[base+pos]=v; sum+=v; sq+=v*v;
    }
    block_reduce2(sum,sq);
    if (threadIdx.x==0){ float* o=pstat+((size_t)bt*8+slab)*2; o[0]=sum; o[1]=sq; }
  } else {
    const float* Sp = Sc + bt*16;
    float muZ=Sp[0], a0=Sp[2], mu1=Sp[3], c1=Sp[4];
    float b2=n2b[0], nb1=mnb1[0], sw1=msw1[0], sb1=msb1[0];
    float s_f=0.f,s_fsq=0.f,s_m=0.f,s_msq=0.f,s_x=0.f;
    for (int pos=threadIdx.x;pos<2048;pos+=256){
      int hl=pos>>7, w=pos&127;
      const float* Th=T+hl*17*2;
      float br=tw[w][0], bi=tw[w][1];
      float rr=br, ri=bi;
      float v=Th[0];
      for (int c=1;c<17;c++){
        v += 2.f*(Th[c*2]*rr - Th[c*2+1]*ri);
        float nr=rr*br-ri*bi; ri=rr*bi+ri*br; rr=nr;
      }
      size_t gi=base+pos;
      float m0v=(z[gi]-muZ)*a0+b2;
      float y=(f1[gi]-mu1)*c1+nb1 + m0v*sw1 + sb1;
      float m1v=gelu_f(y);
      fieldout[gi]=v;
      s_f+=v; s_fsq+=v*v; s_m+=m1v; s_msq+=m1v*m1v; s_x+=v*m1v;
    }
    block_reduce2(s_f,s_fsq);
    block_reduce2(s_m,s_msq);
    s_x = block_reduce1(s_x);
    if (threadIdx.x==0){
      float* o=pstat+((size_t)bt*8+slab)*5;
      o[0]=s_f; o[1]=s_fsq; o[2]=s_m; o[3]=s_msq; o[4]=s_x;
    }
  }
}

// ---- scalar kernels: per-token norm constants ------------------------------
__global__ void k_scalA(const float* __restrict__ pstat, const float* __restrict__ ag,
                        const float* __restrict__ n2g, float* __restrict__ Sc){
  int t=threadIdx.x;
  float sum=0.f,sq=0.f;
  for (int s=0;s<8;s++){ const float* p=pstat+((size_t)t*8+s)*2; sum+=p[0]; sq+=p[1]; }
  const float iN=1.f/NPIX;
  float mu=sum*iN, var=sq*iN-mu*mu;
  float inv=rsqrtf(var+1e-5f);
  float aA=inv*ag[0];
  float var2=aA*aA*var;
  float a0=aA*rsqrtf(var2+1e-5f)*n2g[0];
  float* o=Sc+t*16; o[0]=mu; o[1]=aA; o[2]=a0;
}

__global__ void k_scalB(const float* __restrict__ pstat, const float* __restrict__ mng1,
                        float* __restrict__ Sc){
  int t=threadIdx.x;
  float sum=0.f,sq=0.f;
  for (int s=0;s<8;s++){ const float* p=pstat+((size_t)t*8+s)*2; sum+=p[0]; sq+=p[1]; }
  const float iN=1.f/NPIX;
  float mu=sum*iN, var=sq*iN-mu*mu;
  float c1=rsqrtf(var+1e-5f)*mng1[0];
  float* o=Sc+t*16; o[3]=mu; o[4]=c1;
}

__global__ void k_scalC(const float* __restrict__ pstat, const float* __restrict__ mng2,
                        const float* __restrict__ mnb2, const float* __restrict__ msw2,
                        const float* __restrict__ msb2, const float* __restrict__ outg,
                        float* __restrict__ Sc){
  int t=threadIdx.x;
  float sf=0.f,sfsq=0.f,sm=0.f,smsq=0.f,sx=0.f;
  for (int s=0;s<8;s++){
    const float* p=pstat+((size_t)t*8+s)*5;
    sf+=p[0]; sfsq+=p[1]; sm+=p[2]; smsq+=p[3]; sx+=p[4];
  }
  const float iN=1.f/NPIX;
  float mu2f=sf*iN, var2=sfsq*iN-mu2f*mu2f;
  float c2=rsqrtf(var2+1e-5f)*mng2[0];
  float Em1=sm*iN, Em1sq=smsq*iN, Exm=sx*iN;
  float sw=msw2[0], K=mnb2[0]+msb2[0];
  float Em2=K+sw*Em1;
  float Em2sq = c2*c2*var2 + sw*sw*Em1sq + K*K
              + 2.f*c2*sw*(Exm - mu2f*Em1) + 2.f*K*sw*Em1;
  float var_m2=Em2sq-Em2*Em2;
  float c3=rsqrtf(var_m2+1e-5f)*outg[0];
  float* o=Sc+t*16; o[5]=mu2f; o[6]=c2; o[7]=Em2; o[8]=c3;
}

// ---- column DFT of m0/m1 (recomputed on the fly), 16 rows per block --------
__global__ __launch_bounds__(256) void k_colA(const float* __restrict__ f1, const float* __restrict__ z,
        const float* __restrict__ Sc, const float* __restrict__ n2b,
        const float* __restrict__ mnb1, const float* __restrict__ msw1, const float* __restrict__ msb1,
        float* __restrict__ A, int mode){
  __shared__ float rows[16*128];
  __shared__ float tw[128][2];
  int grow = blockIdx.x*16;
  int t = grow>>7;
  const float* Sp = Sc + t*16;
  float muZ=Sp[0], a0=Sp[2];
  float b2 = n2b[0];
  if (mode==0){
    for (int i=threadIdx.x;i<2048;i+=256){
      float zv = z[(size_t)grow*128 + i];
      rows[i] = (zv-muZ)*a0 + b2;
    }
  } else {
    float mu1=Sp[3], c1=Sp[4];
    float nb=mnb1[0], sw=msw1[0], sb=msb1[0];
    for (int i=threadIdx.x;i<2048;i+=256){
      size_t gi=(size_t)grow*128+i;
      float m0v=(z[gi]-muZ)*a0+b2;
      float y=(f1[gi]-mu1)*c1+nb + m0v*sw + sb;
      rows[i]=gelu_f(y);
    }
  }
  for (int p=threadIdx.x;p<128;p+=256){ float sn,cs; sincosf(-(2.f*PI_F/128.f)*(float)p,&sn,&cs); tw[p][0]=cs; tw[p][1]=sn; }
  __syncthreads();
  for (int e=threadIdx.x;e<16*17;e+=256){
    int r=e/17, c=e%17;
    const float* rp=rows+r*128;
    float re=0.f, im=0.f;
    for (int w=0;w<128;w++){
      int p=(c*w)&127;
      float v=rp[w];
      re+=v*tw[p][0]; im+=v*tw[p][1];
    }
    float* o=A+((size_t)(grow+r)*17+c)*2; o[0]=re; o[1]=im;
  }
}

// ---- forward 32x17 modes, column-group parallel ----------------------------
__global__ __launch_bounds__(256) void k_rowfft32(const float* __restrict__ A, float* __restrict__ spec){
  int s=blockIdx.x, cg=blockIdx.y;
  int c0 = (cg==0)? 0 : (1+cg*4);   // 0,5,9,13
  int nc = (cg==0)? 5 : 4;
  __shared__ float a[128*5*2];
  __shared__ float tw[128][2];
  for (int i=threadIdx.x;i<128*nc*2;i+=256){
    int r=i/(2*nc), q=i%(2*nc);
    a[(r*5+(q>>1))*2+(q&1)] = A[((size_t)(s*128+r)*17 + c0)*2 + q];
  }
  for (int p=threadIdx.x;p<128;p+=256){ float sn,cs; sincosf(-(2.f*PI_F/128.f)*(float)p,&sn,&cs); tw[p][0]=cs; tw[p][1]=sn; }
  __syncthreads();
  const float sc=1.f/16384.f;
  for (int e=threadIdx.x;e<32*nc;e+=256){
    int j=e/nc, cl=e%nc;
    int r=(j<16)? j : (j+96);
    float re=0.f,im=0.f;
    for (int h=0;h<128;h++){
      int p=(r*h)&127;
      float cs=tw[p][0], sn=tw[p][1];
      float ar=a[(h*5+cl)*2], ai=a[(h*5+cl)*2+1];
      re += ar*cs - ai*sn;
      im += ar*sn + ai*cs;
    }
    float* o=spec+((size_t)s*544 + j*17 + c0+cl)*2;
    o[0]=re*sc; o[1]=im*sc;
  }
}

// ---- final: out = norm(m2)+a2, recomputed from z,f1,f2 ---------------------
__global__ __launch_bounds__(256) void k_final2(const float* __restrict__ z, const float* __restrict__ f1,
        const float* __restrict__ f2, const float* __restrict__ Sc,
        const float* __restrict__ ab, const float* __restrict__ n2b,
        const float* __restrict__ mnb1, const float* __restrict__ msw1, const float* __restrict__ msb1,
        const float* __restrict__ mnb2, const float* __restrict__ msw2, const float* __restrict__ msb2,
        const float* __restrict__ outb, float* __restrict__ out){
  int bt=blockIdx.x, slab=blockIdx.y;
  const float* Sp=Sc+bt*16;
  float muZ=Sp[0],aA=Sp[1],a0=Sp[2],mu1=Sp[3],c1=Sp[4],mu2f=Sp[5],c2=Sp[6],mu3=Sp[7],c3=Sp[8];
  float b1=ab[0], b2=n2b[0], nb1=mnb1[0], sw1=msw1[0], sb1=msb1[0];
  float nb2=mnb2[0], sw2=msw2[0], sb2=msb2[0], bo=outb[0];
  size_t base=(size_t)bt*NPIX + (size_t)slab*2048;
  for (int i=threadIdx.x;i<2048;i+=256){
    size_t gi=base+i;
    float zv=z[gi];
    float m0v=(zv-muZ)*a0+b2;
    float a2v=(zv-muZ)*aA+b1;
    float y=(f1[gi]-mu1)*c1+nb1 + m0v*sw1 + sb1;
    float m1v=gelu_f(y);
    float m2v=(f2[gi]-mu2f)*c2+nb2 + m1v*sw2 + sb2;
    out[gi]=(m2v-mu3)*c3+bo+a2v;
  }
}

extern "C" void kernel_launch(void* const* d_in, const int* in_sizes, int n_in,
                              void* d_out, int out_size, void* d_ws, size_t ws_size,
                              hipStream_t stream){
  const float* x        = (const float*)d_in[0];
  const float* key_w    = (const float*)d_in[1];
  const float* key_sw   = (const float*)d_in[2];
  const float* key_sb   = (const float*)d_in[3];
  const float* query_w  = (const float*)d_in[4];
  const float* query_sw = (const float*)d_in[5];
  const float* query_sb = (const float*)d_in[6];
  const float* value_w  = (const float*)d_in[7];
  const float* value_sw = (const float*)d_in[8];
  const float* value_sb = (const float*)d_in[9];
  const float* proj_w   = (const float*)d_in[10];
  const float* proj_sw  = (const float*)d_in[11];
  const float* proj_sb  = (const float*)d_in[12];
  const float* norm1_g  = (const float*)d_in[13];
  const float* norm1_b  = (const float*)d_in[14];
  const float* attn_g   = (const float*)d_in[15];
  const float* attn_b   = (const float*)d_in[16];
  const float* norm2_g  = (const float*)d_in[17];
  const float* norm2_b  = (const float*)d_in[18];
  const float* mw1      = (const float*)d_in[19];
  const float* msw1     = (const float*)d_in[20];
  const float* msb1     = (const float*)d_in[21];
  const float* mng1     = (const float*)d_in[22];
  const float* mnb1     = (const float*)d_in[23];
  const float* mw2      = (const float*)d_in[24];
  const float* msw2     = (const float*)d_in[25];
  const float* msb2     = (const float*)d_in[26];
  const float* mng2     = (const float*)d_in[27];
  const float* mnb2     = (const float*)d_in[28];
  const float* outg     = (const float*)d_in[29];
  const float* outb     = (const float*)d_in[30];
  float* out = (float*)d_out;
  float* ws  = (float*)d_ws;

  size_t off=0;
  float* A   = ws + off; off += (size_t)128*128*33*2;  // column-DFT temp
  float* X64 = ws + off; off += (size_t)128*64*33*2;   // 64x33 spectrum (raw)
  float* X64h= ws + off; off += (size_t)128*64*33*2;   // hermitianized (cols 0,32)
  float* Zq  = ws + off; off += (size_t)128*16*306;
  float* Zk  = ws + off; off += (size_t)128*16*306;
  float* Ue  = ws + off; off += (size_t)4*32*32;
  float* P   = ws + off; off += (size_t)4*16*32*32;
  float* Ra  = ws + off; off += (size_t)4*32*32;
  float* cbv = ws + off; off += (size_t)128;
  float* XPb = ws + off; off += (size_t)2048*544*2;
  float* Sfp = ws + off; off += (size_t)2048*1088;     // per-head Sfin partials
  float* Sf  = ws + off; off += (size_t)128*544*2;
  float* sk  = ws + off; off += (size_t)128*16384;
  float* zf  = ws + off; off += (size_t)128*16384;
  float* fd1 = ws + off; off += (size_t)128*16384;
  float* fd2 = ws + off; off += (size_t)128*16384;
  float* sp  = ws + off; off += (size_t)128*544*2;
  float* pstat0 = ws + off; off += (size_t)128*8*2;
  float* pstatA = ws + off; off += (size_t)128*8*2;
  float* pstatB = ws + off; off += (size_t)128*8*2;
  float* pstatC = ws + off; off += (size_t)128*8*5;
  float* Sc0 = ws + off; off += (size_t)128*2;
  float* Sc  = ws + off; off += (size_t)128*16;

  k_stats0<<<dim3(128,8),256,0,stream>>>(x, pstat0);
  k_scal0<<<1,128,0,stream>>>(pstat0, norm1_g, norm1_b, Sc0);
  k_colfft33<<<1024,256,0,stream>>>(x, Sc0, A);
  k_rowfft64<<<dim3(128,3),256,0,stream>>>(A, X64, X64h);
  k_Z<<<128,256,0,stream>>>(X64, X64h, query_w, query_sw, key_w, key_sw, Zq, Zk);
  k_Ue<<<dim3(4,32,8),256,0,stream>>>(X64h, Ue);
  k_scores_raw<<<dim3(4,16,2),256,0,stream>>>(Zq, Zk, Ue, query_sw, query_sb, key_sw, key_sb, P);
  k_softmax2<<<256,256,0,stream>>>(P);
  k_R<<<dim3(4,32),64,0,stream>>>(P, proj_sw, value_sw, Sc0, Ra, cbv);
  k_XP<<<dim3(4,16,32),256,0,stream>>>(P, X64, XPb);
  k_Sfin<<<dim3(128,16),256,0,stream>>>(XPb, value_w, value_sw, value_sb, proj_w, proj_sw, Sfp);
  k_Sred<<<dim3(128,4),256,0,stream>>>(Sfp, Sf);
  k_skipmix<<<dim3(4,32,4),256,0,stream>>>(x, Ra, cbv, sk);

  k_field<<<dim3(128,8),256,0,stream>>>(Sf, nullptr, sk, x, nullptr, nullptr, nullptr,
      proj_sw, value_sb, proj_sb, nullptr, nullptr, nullptr, nullptr, zf, pstatA, 0);
  k_scalA<<<1,128,0,stream>>>(pstatA, attn_g, norm2_g, Sc);
  k_colA<<<1024,256,0,stream>>>(zf, zf, Sc, norm2_b, mnb1, msw1, msb1, A, 0);
  k_rowfft32<<<dim3(128,4),256,0,stream>>>(A, sp);
  k_field<<<dim3(128,8),256,0,stream>>>(sp, mw1, nullptr, nullptr, nullptr, nullptr, nullptr,
      nullptr, nullptr, nullptr, nullptr, nullptr, nullptr, nullptr, fd1, pstatB, 1);
  k_scalB<<<1,128,0,stream>>>(pstatB, mng1, Sc);
  k_colA<<<1024,256,0,stream>>>(fd1, zf, Sc, norm2_b, mnb1, msw1, msb1, A, 1);
  k_rowfft32<<<dim3(128,4),256,0,stream>>>(A, sp);
  k_field<<<dim3(128,8),256,0,stream>>>(sp, mw2, nullptr, nullptr, fd1, zf, Sc,
      nullptr, nullptr, nullptr, norm2_b, mnb1, msw1, msb1, fd2, pstatC, 2);
  k_scalC<<<1,128,0,stream>>>(pstatC, mng2, mnb2, msw2, msb2, outg, Sc);
  k_final2<<<dim3(128,8),256,0,stream>>>(zf, fd1, fd2, Sc, attn_b, norm2_b,
      mnb1, msw1, msb1, mnb2, msw2, msb2, outb, out);
}